// Round 14
// baseline (346.753 us; speedup 1.0000x reference)
//
#include <hip/hip_runtime.h>
#include <hip/hip_bf16.h>
#include <stdint.h>

// Problem constants
#define NB 8192     // B
#define NL 16       // L
#define NS 256      // S
#define NT 1000     // T
#define NC 500      // C
#define NS5 1280    // 5*S
#define NROWS_JC (NB*15)   // 122880 join rows / inputx rows

typedef __attribute__((ext_vector_type(8))) short bf16x8;
typedef __attribute__((ext_vector_type(4))) float f32x4;

typedef __attribute__((address_space(1))) const void gas_void;
typedef __attribute__((address_space(3))) void las_void;

__device__ __forceinline__ void g2l16(const void* g, void* l) {
  __builtin_amdgcn_global_load_lds((gas_void*)g, (las_void*)l, 16, 0, 0);
}

__device__ __forceinline__ float sigf(float x) { return 1.f / (1.f + __expf(-x)); }
__device__ __forceinline__ float tanhfast(float x) {
  float e = __expf(2.f * fabsf(x));
  float t = 1.f - 2.f / (e + 1.f);
  return copysignf(t, x);
}
__device__ __forceinline__ unsigned short bf16b(float x) {
  __hip_bfloat16 h = __float2bfloat16(x);
  return *reinterpret_cast<unsigned short*>(&h);
}
__device__ __forceinline__ float b2f(unsigned short v) {
  union { unsigned u; float f; } x;
  x.u = (unsigned)v << 16;
  return x.f;
}

// Gate-interleaved packed-column decode, 5-gate (quarter-based so each
// col-wave is gate-complete for 16 units).
__device__ __forceinline__ int origcol(int slice, int nc) {
  int q = nc / 80, rem = nc % 80;
  int g = rem / 16, u16 = rem % 16;
  int U = slice * 64 + q * 16 + u16;
  return g * 256 + U;
}
// 3-gate variant (level 0: only a,i,o live; f1/f2 multiply c==0).
__device__ __forceinline__ int origcol3(int slice, int nc) {
  int q = nc / 48, rem = nc % 48;
  int g = rem / 16, u16 = rem % 16;
  int U = slice * 64 + q * 16 + u16;
  const int G[3] = {0, 1, 4};  // a, i, o
  return G[g] * 256 + U;
}

// ---------------- Fused prologue ----------------
#define PB_INPUTX (NROWS_JC / 8)          // 15360
#define PB_LN     (PB_INPUTX + NT)        // +1000
#define PB_W12    (PB_LN + 480)           // +480
#define PB_W12L0  (PB_W12 + 288)          // +288 (4*24*192*4/256)
#define PB_FCW    (PB_W12L0 + 64)         // +64
#define PB_TOTAL  (PB_FCW + 8)            // +8 (bias5: 5 blocks, bias3: 3)

__global__ __launch_bounds__(256) void prologue_kernel(
    const float* __restrict__ jc, const float* __restrict__ jcW,
    const float* __restrict__ jcb, unsigned short* __restrict__ inpx,
    const float* __restrict__ emb, const float* __restrict__ lng,
    const float* __restrict__ lnb, unsigned short* __restrict__ ob16,
    const float* __restrict__ W1, const float* __restrict__ W2,
    const float* __restrict__ W0, unsigned short* __restrict__ w12p,
    unsigned short* __restrict__ w12p0,
    const float* __restrict__ fcW, unsigned short* __restrict__ fcwp,
    const float* __restrict__ b1, const float* __restrict__ b2,
    const float* __restrict__ b0, float* __restrict__ bias_zp,
    float* __restrict__ bias_zp3) {
  __shared__ float rs[4], rs2[4];
  const int bid = blockIdx.x;
  const int tid = threadIdx.x;

  if (bid < PB_INPUTX) {
    // ---- inputx: sparse join (R9-proven single-bit gather, 2 rows/wave) ----
    int wv = tid >> 6, lane = tid & 63;
    size_t row0 = (size_t)bid * 8 + wv * 2;
    const float* jr0 = jc + row0 * NC;
    const float* jr1 = jc + (row0 + 1) * NC;
    float4 p0 = *(const float4*)(jr0 + lane * 4);
    float4 q0 = *(const float4*)(jr1 + lane * 4);
    float4 p1 = make_float4(0.f, 0.f, 0.f, 0.f);
    float4 q1 = make_float4(0.f, 0.f, 0.f, 0.f);
    if (lane < 61) {
      p1 = *(const float4*)(jr0 + 256 + lane * 4);
      q1 = *(const float4*)(jr1 + 256 + lane * 4);
    }
    const float4 jb = *(const float4*)(jcb + lane * 4);
    float a0 = jb.x, a1 = jb.y, a2 = jb.z, a3 = jb.w;
    float c0 = jb.x, c1 = jb.y, c2 = jb.z, c3 = jb.w;

#define GATHER_MASK(val, cbase, d0, d1, d2, d3)                       \
    {                                                                 \
      unsigned long long m = __ballot((val) != 0.f);                  \
      while (m) {                                                     \
        int l = __ffsll(m) - 1;                                       \
        m &= m - 1;                                                   \
        int c = (cbase) + l * 4;                                      \
        const float4 w = *(const float4*)(jcW + (size_t)c * NS + lane * 4); \
        d0 += w.x; d1 += w.y; d2 += w.z; d3 += w.w;                   \
      }                                                               \
    }
    GATHER_MASK(p0.x, 0, a0, a1, a2, a3) GATHER_MASK(p0.y, 1, a0, a1, a2, a3)
    GATHER_MASK(p0.z, 2, a0, a1, a2, a3) GATHER_MASK(p0.w, 3, a0, a1, a2, a3)
    GATHER_MASK(p1.x, 256, a0, a1, a2, a3) GATHER_MASK(p1.y, 257, a0, a1, a2, a3)
    GATHER_MASK(p1.z, 258, a0, a1, a2, a3) GATHER_MASK(p1.w, 259, a0, a1, a2, a3)
    GATHER_MASK(q0.x, 0, c0, c1, c2, c3) GATHER_MASK(q0.y, 1, c0, c1, c2, c3)
    GATHER_MASK(q0.z, 2, c0, c1, c2, c3) GATHER_MASK(q0.w, 3, c0, c1, c2, c3)
    GATHER_MASK(q1.x, 256, c0, c1, c2, c3) GATHER_MASK(q1.y, 257, c0, c1, c2, c3)
    GATHER_MASK(q1.z, 258, c0, c1, c2, c3) GATHER_MASK(q1.w, 259, c0, c1, c2, c3)
#undef GATHER_MASK

    ushort4 o;
    o.x = bf16b(a0); o.y = bf16b(a1); o.z = bf16b(a2); o.w = bf16b(a3);
    *(ushort4*)(inpx + row0 * NS + lane * 4) = o;
    o.x = bf16b(c0); o.y = bf16b(c1); o.z = bf16b(c2); o.w = bf16b(c3);
    *(ushort4*)(inpx + (row0 + 1) * NS + lane * 4) = o;
  } else if (bid < PB_LN) {
    // ---- ln: LayerNorm of the embedding table (bf16 out) ----
    int t = bid - PB_INPUTX;
    int i = tid;
    int lane = i & 63, wv = i >> 6;
    float x = emb[t * NS + i];
    float s = x, s2 = x * x;
    for (int o = 1; o < 64; o <<= 1) {
      s += __shfl_xor(s, o);
      s2 += __shfl_xor(s2, o);
    }
    if (lane == 0) { rs[wv] = s; rs2[wv] = s2; }
    __syncthreads();
    float S = rs[0] + rs[1] + rs[2] + rs[3];
    float S2 = rs2[0] + rs2[1] + rs2[2] + rs2[3];
    float mu = S * (1.f / NS);
    float var = S2 * (1.f / NS) - mu * mu;
    float y = (x - mu) * rsqrtf(var + 1e-5f) * lng[i] + lnb[i];
    ob16[t * NS + i] = bf16b(y);
  } else if (bid < PB_W12) {
    // ---- pack_w12 (5-gate) ----
    int e = (bid - PB_LN) * 256 + tid;  // < 122880
    int kg = e & 3;
    int r = e >> 2;
    int nc = r % 320; r /= 320;
    int kc = r % 24;
    int slice = r / 24;
    int oc = origcol(slice, nc);
    int kbase = kc * 32 + kg * 8;
    unsigned short tmp[8];
#pragma unroll
    for (int j = 0; j < 8; ++j) {
      int k = kbase + j;
      float x;
      if (k < 256) x = W1[(size_t)k * NS5 + oc];
      else if (k < 512) x = W2[(size_t)(k - 256) * NS5 + oc];
      else x = W0[(size_t)(k - 512) * NS5 + oc];
      tmp[j] = bf16b(x);
    }
    ushort4 v0 = make_ushort4(tmp[0], tmp[1], tmp[2], tmp[3]);
    ushort4 v1 = make_ushort4(tmp[4], tmp[5], tmp[6], tmp[7]);
    size_t dst = (size_t)(slice * 24 + kc) * 20480 + (size_t)nc * 64 + kg * 16;
    *(ushort4*)((char*)w12p + dst) = v0;
    *(ushort4*)((char*)w12p + dst + 8) = v1;
  } else if (bid < PB_W12L0) {
    // ---- pack_w12_l0 (3-gate a,i,o) ----
    int e = (bid - PB_W12) * 256 + tid;  // < 73728
    int kg = e & 3;
    int r = e >> 2;
    int nc = r % 192; r /= 192;
    int kc = r % 24;
    int slice = r / 24;
    int oc = origcol3(slice, nc);
    int kbase = kc * 32 + kg * 8;
    unsigned short tmp[8];
#pragma unroll
    for (int j = 0; j < 8; ++j) {
      int k = kbase + j;
      float x;
      if (k < 256) x = W1[(size_t)k * NS5 + oc];
      else if (k < 512) x = W2[(size_t)(k - 256) * NS5 + oc];
      else x = W0[(size_t)(k - 512) * NS5 + oc];
      tmp[j] = bf16b(x);
    }
    ushort4 v0 = make_ushort4(tmp[0], tmp[1], tmp[2], tmp[3]);
    ushort4 v1 = make_ushort4(tmp[4], tmp[5], tmp[6], tmp[7]);
    size_t dst = (size_t)(slice * 24 + kc) * 12288 + (size_t)nc * 64 + kg * 16;
    *(ushort4*)((char*)w12p0 + dst) = v0;
    *(ushort4*)((char*)w12p0 + dst + 8) = v1;
  } else if (bid < PB_FCW) {
    // ---- pack_fcw ----
    int e = (bid - PB_W12L0) * 256 + tid;  // < 16384
    int kg = e & 3;
    int r = e >> 2;
    int nc = r & 255;
    int kc = r >> 8;
    int kbase = kc * 32 + kg * 8;
    unsigned short tmp[8];
#pragma unroll
    for (int j = 0; j < 8; ++j) tmp[j] = bf16b(fcW[(size_t)(kbase + j) * NS + nc]);
    ushort4 v0 = make_ushort4(tmp[0], tmp[1], tmp[2], tmp[3]);
    ushort4 v1 = make_ushort4(tmp[4], tmp[5], tmp[6], tmp[7]);
    size_t dst = (size_t)kc * 16384 + (size_t)nc * 64 + kg * 16;
    *(ushort4*)((char*)fcwp + dst) = v0;
    *(ushort4*)((char*)fcwp + dst + 8) = v1;
  } else if (bid < PB_FCW + 5) {
    // ---- bias5 ----
    int pc = (bid - PB_FCW) * 256 + tid;
    if (pc < NS5) {
      int slice = pc / 320, nc = pc % 320;
      int oc = origcol(slice, nc);
      bias_zp[pc] = b1[oc] + b2[oc] + b0[oc];
    }
  } else {
    // ---- bias3 ----
    int pc = (bid - PB_FCW - 5) * 256 + tid;
    if (pc < 768) {
      int slice = pc / 192, nc = pc % 192;
      int oc = origcol3(slice, nc);
      bias_zp3[pc] = b1[oc] + b2[oc] + b0[oc];
    }
  }
}

// ---------------- Level 0: 64-row x 3-gate, high-occupancy ----------------
// R13 showed L0 is NOT MFMA/B-bound: phases serialize at 2 blocks/CU.
// This kernel: acc[4][3]=48 AGPR + ~64 VGPR ~= 112 unified -> 4 waves/SIMD
// (launch_bounds(256,4)), LDS 16KB -> 4 blocks/CU. Block = 64 rows x 192
// packed cols (one slice, gates a,i,o); c==0 so f1/f2 are dead.
__global__ __launch_bounds__(256, 4) void level0_kernel(
    const unsigned short* __restrict__ h_in,  // ln_b16 table
    const unsigned short* __restrict__ inpx,  // (B*15,256) bf16
    const unsigned short* __restrict__ w12p0, // 3-gate packed images
    const float* __restrict__ bias_zp3,       // (768)
    unsigned short* __restrict__ h_out,       // (65536,256) bf16
    unsigned* __restrict__ c_out,             // (32768,256) u32 pairs
    const int* __restrict__ leaf) {
  __shared__ __align__(1024) char ldsA[2 * 8192];
  const int tid = threadIdx.x, lane = tid & 63, wv = tid >> 6;  // wv = col-group
  const int m0 = blockIdx.x * 64;
  const int slice = blockIdx.y;

  f32x4 acc[4][3];
#pragma unroll
  for (int a = 0; a < 4; ++a)
#pragma unroll
    for (int t = 0; t < 3; ++t) acc[a][t] = (f32x4){0.f, 0.f, 0.f, 0.f};

  const int rl = wv * 16 + (lane >> 2);                // row 0..63
  const int ss = (lane & 3) ^ ((rl >> 1) & 3);         // pre-swizzled 16B chunk
  const int m = m0 + rl;
  const char* hsrc0 = (const char*)h_in + ((size_t)leaf[2 * m] * 512 + (size_t)ss * 16);
  const char* hsrc1 = (const char*)h_in + ((size_t)leaf[2 * m + 1] * 512 + (size_t)ss * 16);
  // L0: log2n=3, joff=0
  const char* xsrc = (const char*)inpx +
      (((size_t)(m >> 3) * 15 + (m & 7)) * 512 + (size_t)ss * 16);
  char* adst = ldsA + wv * 1024;

  auto srcA = [&](int kc) -> const char* {
    return (kc < 8) ? hsrc0 + kc * 64
         : (kc < 16) ? hsrc1 + (kc - 8) * 64
                     : xsrc + (kc - 16) * 64;
  };
  auto stageA = [&](int kt, int buf) {  // stages kc = 2kt, 2kt+1 (2 DMAs)
    g2l16(srcA(2 * kt), adst + buf * 8192);
    g2l16(srcA(2 * kt + 1), adst + buf * 8192 + 4096);
  };

  const int aoff = (lane & 15) * 64 + (((lane >> 4) ^ ((lane >> 1) & 3)) << 4);
  const char* gB = (const char*)w12p0 + (size_t)slice * 24 * 12288 +
                   (size_t)(wv * 48 + (lane & 15)) * 64 + (size_t)(lane >> 4) * 16;

  bf16x8 bcur[3], bnxt[3];
  auto loadB = [&](int kc, bf16x8* dst) {
    const char* gk = gB + (size_t)kc * 12288;
    dst[0] = *(const bf16x8*)(gk);
    dst[1] = *(const bf16x8*)(gk + 1024);
    dst[2] = *(const bf16x8*)(gk + 2048);
  };

#define CLUSTER0(pA, bset)                                                          \
  {                                                                                 \
    bf16x8 a0 = *(const bf16x8*)(pA);                                               \
    bf16x8 a1 = *(const bf16x8*)((pA) + 1024);                                      \
    bf16x8 a2 = *(const bf16x8*)((pA) + 2048);                                      \
    bf16x8 a3 = *(const bf16x8*)((pA) + 3072);                                      \
    _Pragma("unroll")                                                               \
    for (int g = 0; g < 3; ++g) {                                                   \
      acc[0][g] = __builtin_amdgcn_mfma_f32_16x16x32_bf16(a0, bset[g], acc[0][g], 0, 0, 0); \
      acc[1][g] = __builtin_amdgcn_mfma_f32_16x16x32_bf16(a1, bset[g], acc[1][g], 0, 0, 0); \
      acc[2][g] = __builtin_amdgcn_mfma_f32_16x16x32_bf16(a2, bset[g], acc[2][g], 0, 0, 0); \
      acc[3][g] = __builtin_amdgcn_mfma_f32_16x16x32_bf16(a3, bset[g], acc[3][g], 0, 0, 0); \
    }                                                                               \
  }

  stageA(0, 0);
  loadB(0, bcur);
  asm volatile("s_waitcnt vmcnt(0)" ::: "memory");
  __builtin_amdgcn_s_barrier();

  for (int kt = 0; kt < 12; ++kt) {
    const int buf = kt & 1;
    stageA(kt < 11 ? kt + 1 : 11, buf ^ 1);
    __builtin_amdgcn_sched_barrier(0);
    loadB(2 * kt + 1, bnxt);
    const char* pA = ldsA + buf * 8192 + aoff;
    CLUSTER0(pA, bcur);
    loadB(2 * kt + 2 < 24 ? 2 * kt + 2 : 0, bcur);
    CLUSTER0(pA + 4096, bnxt);
    __builtin_amdgcn_sched_barrier(0);
    asm volatile("s_waitcnt vmcnt(3)" ::: "memory");
    __builtin_amdgcn_sched_barrier(0);
    __builtin_amdgcn_s_barrier();
  }
#undef CLUSTER0

  // ---- Epilogue: c==0 cell ----
  float bias[3];
#pragma unroll
  for (int g = 0; g < 3; ++g)
    bias[g] = bias_zp3[slice * 192 + wv * 48 + g * 16 + (lane & 15)];
  const int u = slice * 64 + wv * 16 + (lane & 15);

#pragma unroll
  for (int rt = 0; rt < 4; ++rt) {
    const int base = m0 + rt * 16 + (lane >> 4) * 4;  // 4 consecutive rows
    float hv[4], cv[4];
#pragma unroll
    for (int r = 0; r < 4; ++r) {
      float za = acc[rt][0][r] + bias[0];
      float zi = acc[rt][1][r] + bias[1];
      float zo = acc[rt][2][r] + bias[2];
      float cnew = tanhfast(za) * sigf(zi);
      cv[r] = cnew;
      hv[r] = sigf(zo) * tanhfast(cnew);
    }
#pragma unroll
    for (int r = 0; r < 4; ++r)
      h_out[(size_t)(base + r) * NS + u] = bf16b(hv[r]);
    const size_t pb = (size_t)(base >> 1) * NS + u;
    c_out[pb] = (unsigned)bf16b(cv[0]) | ((unsigned)bf16b(cv[1]) << 16);
    c_out[pb + NS] = (unsigned)bf16b(cv[2]) | ((unsigned)bf16b(cv[3]) << 16);
  }
}

// ---------------- Fused tree-level GEMM + LSTM cell (5-gate, R12-exact) ----
// Block: 128 rows x 320 packed cols, 4 waves (col-groups); wave tile 128x80.
// acc[8][5] in AGPRs; A: LDS 32KB dbuf, 4 DMAs/iter; B: reg rotating prefetch.
template <bool FIRST, bool LAST>
__global__ __launch_bounds__(256, 2) void level_kernel(
    const unsigned short* __restrict__ h_in,
    const unsigned* __restrict__ c_in,        // (M,256) u32 pairs
    const unsigned short* __restrict__ inpx,
    const unsigned short* __restrict__ w12p,
    const float* __restrict__ bias_zp,
    unsigned short* __restrict__ h_out,
    unsigned* __restrict__ c_out,
    unsigned short* __restrict__ state_out,
    const int* __restrict__ leaf,
    int log2n, int joff) {
  __shared__ __align__(1024) char ldsA[2 * 16384];
  const int tid = threadIdx.x, lane = tid & 63, wv = tid >> 6;
  const int m0 = blockIdx.x * 128;
  const int slice = blockIdx.y;
  const int n = 1 << log2n;

  f32x4 acc[8][5];
#pragma unroll
  for (int a = 0; a < 8; ++a)
#pragma unroll
    for (int t = 0; t < 5; ++t) acc[a][t] = (f32x4){0.f, 0.f, 0.f, 0.f};

  const int rl64 = wv * 16 + (lane >> 2);
  const int ss = (lane & 3) ^ ((rl64 >> 1) & 3);
  const int mlo = m0 + rl64, mhi = mlo + 64;
  const char* h0lo; const char* h1lo; const char* h0hi; const char* h1hi;
  if (FIRST) {
    h0lo = (const char*)h_in + ((size_t)leaf[2 * mlo] * 512 + (size_t)ss * 16);
    h1lo = (const char*)h_in + ((size_t)leaf[2 * mlo + 1] * 512 + (size_t)ss * 16);
    h0hi = (const char*)h_in + ((size_t)leaf[2 * mhi] * 512 + (size_t)ss * 16);
    h1hi = (const char*)h_in + ((size_t)leaf[2 * mhi + 1] * 512 + (size_t)ss * 16);
  } else {
    h0lo = (const char*)h_in + ((size_t)mlo * 1024 + (size_t)ss * 16);
    h1lo = h0lo;
    h0hi = (const char*)h_in + ((size_t)mhi * 1024 + (size_t)ss * 16);
    h1hi = h0hi;
  }
  const char* xlo = (const char*)inpx +
      (((size_t)(mlo >> log2n) * 15 + joff + (mlo & (n - 1))) * 512 + (size_t)ss * 16);
  const char* xhi = (const char*)inpx +
      (((size_t)(mhi >> log2n) * 15 + joff + (mhi & (n - 1))) * 512 + (size_t)ss * 16);
  char* adst = ldsA + wv * 1024;

  auto srcA = [&](int kc, int j) -> const char* {
    const char* h0 = j ? h0hi : h0lo;
    const char* h1 = j ? h1hi : h1lo;
    const char* xs = j ? xhi : xlo;
    if (FIRST) {
      return (kc < 8) ? h0 + kc * 64
           : (kc < 16) ? h1 + (kc - 8) * 64
                       : xs + (kc - 16) * 64;
    }
    return (kc < 16) ? h0 + kc * 64 : xs + (kc - 16) * 64;
  };
  auto stageA = [&](int kt, int buf) {
    char* db = adst + buf * 16384;
    g2l16(srcA(2 * kt, 0), db);
    g2l16(srcA(2 * kt, 1), db + 4096);
    g2l16(srcA(2 * kt + 1, 0), db + 8192);
    g2l16(srcA(2 * kt + 1, 1), db + 12288);
  };

  const int aoff = (lane & 15) * 64 + (((lane >> 4) ^ ((lane >> 1) & 3)) << 4);
  const char* gB = (const char*)w12p + (size_t)slice * 24 * 20480 +
                   (size_t)(wv * 80 + (lane & 15)) * 64 + (size_t)(lane >> 4) * 16;

  bf16x8 bcur[5], bnxt[5];
  auto loadB = [&](int kc, bf16x8* dst) {
    const char* gk = gB + (size_t)kc * 20480;
#pragma unroll
    for (int g = 0; g < 5; ++g) dst[g] = *(const bf16x8*)(gk + g * 1024);
  };

#define CLUSTER(pA, bset)                                                           \
  {                                                                                 \
    bf16x8 a0 = *(const bf16x8*)(pA);                                               \
    bf16x8 a1 = *(const bf16x8*)((pA) + 1024);                                      \
    bf16x8 a2 = *(const bf16x8*)((pA) + 2048);                                      \
    bf16x8 a3 = *(const bf16x8*)((pA) + 3072);                                      \
    bf16x8 a4 = *(const bf16x8*)((pA) + 4096);                                      \
    bf16x8 a5 = *(const bf16x8*)((pA) + 5120);                                      \
    bf16x8 a6 = *(const bf16x8*)((pA) + 6144);                                      \
    bf16x8 a7 = *(const bf16x8*)((pA) + 7168);                                      \
    _Pragma("unroll")                                                               \
    for (int g = 0; g < 5; ++g) {                                                   \
      acc[0][g] = __builtin_amdgcn_mfma_f32_16x16x32_bf16(a0, bset[g], acc[0][g], 0, 0, 0); \
      acc[1][g] = __builtin_amdgcn_mfma_f32_16x16x32_bf16(a1, bset[g], acc[1][g], 0, 0, 0); \
      acc[2][g] = __builtin_amdgcn_mfma_f32_16x16x32_bf16(a2, bset[g], acc[2][g], 0, 0, 0); \
      acc[3][g] = __builtin_amdgcn_mfma_f32_16x16x32_bf16(a3, bset[g], acc[3][g], 0, 0, 0); \
      acc[4][g] = __builtin_amdgcn_mfma_f32_16x16x32_bf16(a4, bset[g], acc[4][g], 0, 0, 0); \
      acc[5][g] = __builtin_amdgcn_mfma_f32_16x16x32_bf16(a5, bset[g], acc[5][g], 0, 0, 0); \
      acc[6][g] = __builtin_amdgcn_mfma_f32_16x16x32_bf16(a6, bset[g], acc[6][g], 0, 0, 0); \
      acc[7][g] = __builtin_amdgcn_mfma_f32_16x16x32_bf16(a7, bset[g], acc[7][g], 0, 0, 0); \
    }                                                                               \
  }

  stageA(0, 0);
  loadB(0, bcur);
  asm volatile("s_waitcnt vmcnt(0)" ::: "memory");
  __builtin_amdgcn_s_barrier();

  for (int kt = 0; kt < 12; ++kt) {
    const int buf = kt & 1;
    stageA(kt < 11 ? kt + 1 : 11, buf ^ 1);
    __builtin_amdgcn_sched_barrier(0);
    loadB(2 * kt + 1, bnxt);
    const char* pA = ldsA + buf * 16384 + aoff;
    CLUSTER(pA, bcur);
    loadB(2 * kt + 2 < 24 ? 2 * kt + 2 : 0, bcur);
    CLUSTER(pA + 8192, bnxt);
    __builtin_amdgcn_sched_barrier(0);
    asm volatile("s_waitcnt vmcnt(5)" ::: "memory");
    __builtin_amdgcn_sched_barrier(0);
    __builtin_amdgcn_s_barrier();
  }
#undef CLUSTER

  float bias[5];
#pragma unroll
  for (int g = 0; g < 5; ++g)
    bias[g] = bias_zp[slice * 320 + wv * 80 + g * 16 + (lane & 15)];
  const int u = slice * 64 + wv * 16 + (lane & 15);

#pragma unroll
  for (int rt = 0; rt < 8; ++rt) {
    const int base = m0 + rt * 16 + (lane >> 4) * 4;
    float hv[4], cv[4];
#pragma unroll
    for (int r = 0; r < 4; ++r) {
      int row = base + r;
      float za = acc[rt][0][r] + bias[0];
      float zi = acc[rt][1][r] + bias[1];
      float zo = acc[rt][4][r] + bias[4];
      float cnew = tanhfast(za) * sigf(zi);
      if (!FIRST) {
        float zf1 = acc[rt][2][r] + bias[2];
        float zf2 = acc[rt][3][r] + bias[3];
        unsigned pc = c_in[(size_t)row * NS + u];
        float cl = b2f((unsigned short)(pc & 0xffff));
        float cr = b2f((unsigned short)(pc >> 16));
        cnew += sigf(zf1) * cl + sigf(zf2) * cr;
      }
      cv[r] = cnew;
      hv[r] = sigf(zo) * tanhfast(cnew);
    }
    if (LAST) {
#pragma unroll
      for (int r = 0; r < 4; ++r)
        state_out[(size_t)(base + r) * NS + u] = bf16b(hv[r]);
    } else {
#pragma unroll
      for (int r = 0; r < 4; ++r)
        h_out[(size_t)(base + r) * NS + u] = bf16b(hv[r]);
      const size_t pb = (size_t)(base >> 1) * NS + u;
      c_out[pb] = (unsigned)bf16b(cv[0]) | ((unsigned)bf16b(cv[1]) << 16);
      c_out[pb + NS] = (unsigned)bf16b(cv[2]) | ((unsigned)bf16b(cv[3]) << 16);
    }
  }
}

// ---------------- Final head via MFMA ----------------
__global__ __launch_bounds__(256, 2) void fc_mfma(
    const unsigned short* __restrict__ stateb,
    const unsigned short* __restrict__ ln_b16,
    const int* __restrict__ action_ids, const unsigned short* __restrict__ fcwp,
    const float* __restrict__ fcb, const float* __restrict__ outW,
    const float* __restrict__ outb, float* __restrict__ out) {
  __shared__ __align__(1024) char ldsA[2 * 8192];
  __shared__ float red[64][4];
  const int tid = threadIdx.x, lane = tid & 63, wv = tid >> 6;
  const int m0 = blockIdx.x * 64;

  f32x4 acc[4][4];
#pragma unroll
  for (int a = 0; a < 4; ++a)
#pragma unroll
    for (int t = 0; t < 4; ++t) acc[a][t] = (f32x4){0.f, 0.f, 0.f, 0.f};

  const int rl = wv * 16 + (lane >> 2);
  const int ss = (lane & 3) ^ ((rl >> 1) & 3);
  const int m = m0 + rl;
  const char* src0 = (const char*)stateb + ((size_t)m * 512 + (size_t)ss * 16);
  const char* src1 =
      (const char*)ln_b16 + ((size_t)action_ids[m] * 512 + (size_t)ss * 16);
  char* adst = ldsA + wv * 1024;

  auto srcA = [&](int kc) -> const char* {
    return (kc < 8) ? src0 + kc * 64 : src1 + (kc - 8) * 64;
  };
  auto stageA = [&](int kt, int buf) {
    g2l16(srcA(2 * kt), adst + buf * 8192);
    g2l16(srcA(2 * kt + 1), adst + buf * 8192 + 4096);
  };

  const int aoff = (lane & 15) * 64 + (((lane >> 4) ^ ((lane >> 1) & 3)) << 4);
  const char* gB = (const char*)fcwp +
                   (size_t)(wv * 64 + (lane & 15)) * 64 + (size_t)(lane >> 4) * 16;

  bf16x8 bcur[4], bnxt[4];
  auto loadB = [&](int kc, bf16x8* dst) {
    const char* gk = gB + (size_t)kc * 16384;
#pragma unroll
    for (int t = 0; t < 4; ++t) dst[t] = *(const bf16x8*)(gk + t * 1024);
  };

  stageA(0, 0);
  loadB(0, bcur);
  asm volatile("s_waitcnt vmcnt(0)" ::: "memory");
  __builtin_amdgcn_s_barrier();

  for (int kt = 0; kt < 8; ++kt) {
    const int buf = kt & 1;
    stageA(kt < 7 ? kt + 1 : 7, buf ^ 1);
    __builtin_amdgcn_sched_barrier(0);
    loadB(2 * kt + 1, bnxt);
    const char* pA = ldsA + buf * 8192 + aoff;
    bf16x8 a0 = *(const bf16x8*)(pA);
    bf16x8 a1 = *(const bf16x8*)(pA + 1024);
    bf16x8 a2 = *(const bf16x8*)(pA + 2048);
    bf16x8 a3 = *(const bf16x8*)(pA + 3072);
#pragma unroll
    for (int t = 0; t < 4; ++t) {
      acc[0][t] = __builtin_amdgcn_mfma_f32_16x16x32_bf16(a0, bcur[t], acc[0][t], 0, 0, 0);
      acc[1][t] = __builtin_amdgcn_mfma_f32_16x16x32_bf16(a1, bcur[t], acc[1][t], 0, 0, 0);
      acc[2][t] = __builtin_amdgcn_mfma_f32_16x16x32_bf16(a2, bcur[t], acc[2][t], 0, 0, 0);
      acc[3][t] = __builtin_amdgcn_mfma_f32_16x16x32_bf16(a3, bcur[t], acc[3][t], 0, 0, 0);
    }
    loadB(2 * kt + 2 < 16 ? 2 * kt + 2 : 0, bcur);
    bf16x8 c0 = *(const bf16x8*)(pA + 4096);
    bf16x8 c1 = *(const bf16x8*)(pA + 5120);
    bf16x8 c2 = *(const bf16x8*)(pA + 6144);
    bf16x8 c3 = *(const bf16x8*)(pA + 7168);
#pragma unroll
    for (int t = 0; t < 4; ++t) {
      acc[0][t] = __builtin_amdgcn_mfma_f32_16x16x32_bf16(c0, bnxt[t], acc[0][t], 0, 0, 0);
      acc[1][t] = __builtin_amdgcn_mfma_f32_16x16x32_bf16(c1, bnxt[t], acc[1][t], 0, 0, 0);
      acc[2][t] = __builtin_amdgcn_mfma_f32_16x16x32_bf16(c2, bnxt[t], acc[2][t], 0, 0, 0);
      acc[3][t] = __builtin_amdgcn_mfma_f32_16x16x32_bf16(c3, bnxt[t], acc[3][t], 0, 0, 0);
    }
    __builtin_amdgcn_sched_barrier(0);
    asm volatile("s_waitcnt vmcnt(4)" ::: "memory");
    __builtin_amdgcn_sched_barrier(0);
    __builtin_amdgcn_s_barrier();
  }

  float fb[4], ow[4];
#pragma unroll
  for (int t = 0; t < 4; ++t) {
    int col = wv * 64 + t * 16 + (lane & 15);
    fb[t] = fcb[col];
    ow[t] = outW[col];
  }
#pragma unroll
  for (int rt = 0; rt < 4; ++rt) {
#pragma unroll
    for (int r = 0; r < 4; ++r) {
      float s = 0.f;
#pragma unroll
      for (int t = 0; t < 4; ++t)
        s += fmaxf(acc[rt][t][r] + fb[t], 0.f) * ow[t];
      s += __shfl_xor(s, 1);
      s += __shfl_xor(s, 2);
      s += __shfl_xor(s, 4);
      s += __shfl_xor(s, 8);
      if ((lane & 15) == 0) red[rt * 16 + (lane >> 4) * 4 + r][wv] = s;
    }
  }
  __syncthreads();
  if (tid < 64)
    out[m0 + tid] = red[tid][0] + red[tid][1] + red[tid][2] + red[tid][3] + outb[0];
}

extern "C" void kernel_launch(void* const* d_in, const int* in_sizes, int n_in,
                              void* d_out, int out_size, void* d_ws, size_t ws_size,
                              hipStream_t stream) {
  const int* leaf_ids = (const int*)d_in[0];
  const int* action_ids = (const int*)d_in[1];
  const float* join_cols = (const float*)d_in[2];
  const float* emb = (const float*)d_in[3];
  const float* ln_g = (const float*)d_in[4];
  const float* ln_b = (const float*)d_in[5];
  const float* jc_W = (const float*)d_in[6];
  const float* jc_b = (const float*)d_in[7];
  const float* W1 = (const float*)d_in[8];
  const float* b1 = (const float*)d_in[9];
  const float* W2 = (const float*)d_in[10];
  const float* b2 = (const float*)d_in[11];
  const float* W0 = (const float*)d_in[12];
  const float* b0 = (const float*)d_in[13];
  const float* fc_W = (const float*)d_in[14];
  const float* fc_b = (const float*)d_in[15];
  const float* out_W = (const float*)d_in[16];
  const float* out_b = (const float*)d_in[17];

  char* ws = (char*)d_ws;
  size_t o = 0;
  auto alloc = [&](size_t bytes) {
    size_t r = o;
    o += (bytes + 255) & ~(size_t)255;
    return r;
  };
  unsigned short* ln_b16 = (unsigned short*)(ws + alloc((size_t)NT * NS * 2));
  unsigned short* w12p = (unsigned short*)(ws + alloc((size_t)4 * 24 * 20480));
  unsigned short* w12p0 = (unsigned short*)(ws + alloc((size_t)4 * 24 * 12288));
  unsigned short* fcwp = (unsigned short*)(ws + alloc((size_t)16 * 16384));
  float* bias_zp = (float*)(ws + alloc((size_t)NS5 * 4));
  float* bias_zp3 = (float*)(ws + alloc((size_t)768 * 4));
  unsigned short* inpx = (unsigned short*)(ws + alloc((size_t)NROWS_JC * NS * 2));
  unsigned short* hX = (unsigned short*)(ws + alloc((size_t)NB * 8 * NS * 2));
  unsigned short* hY = (unsigned short*)(ws + alloc((size_t)NB * 4 * NS * 2));
  unsigned* cX = (unsigned*)(ws + alloc((size_t)NB * 8 * NS * 2));
  unsigned* cY = (unsigned*)(ws + alloc((size_t)NB * 4 * NS * 2));
  unsigned short* stateb = (unsigned short*)(ws + alloc((size_t)NB * NS * 2));
  (void)ws_size; (void)in_sizes; (void)n_in; (void)out_size;

  // Fused prologue
  prologue_kernel<<<PB_TOTAL, 256, 0, stream>>>(
      join_cols, jc_W, jc_b, inpx, emb, ln_g, ln_b, ln_b16, W1, W2, W0, w12p,
      w12p0, fc_W, fcwp, b1, b2, b0, bias_zp, bias_zp3);

  // Level 0: 64-row x 3-gate, 4 blocks/CU (M=65536)
  level0_kernel<<<dim3(1024, 4), 256, 0, stream>>>(
      ln_b16, inpx, w12p0, bias_zp3, hX, cX, leaf_ids);
  // Level 1: n=4, off=8, M=32768
  level_kernel<false, false><<<dim3(256, 4), 256, 0, stream>>>(
      hX, cX, inpx, w12p, bias_zp, hY, cY, nullptr, leaf_ids, 2, 8);
  // Level 2: n=2, off=12, M=16384
  level_kernel<false, false><<<dim3(128, 4), 256, 0, stream>>>(
      hY, cY, inpx, w12p, bias_zp, hX, cX, nullptr, leaf_ids, 1, 12);
  // Level 3: n=1, off=14, M=8192 -> state bf16
  level_kernel<false, true><<<dim3(64, 4), 256, 0, stream>>>(
      hX, cX, inpx, w12p, bias_zp, nullptr, nullptr, stateb, leaf_ids, 0, 14);

  fc_mfma<<<NB / 64, 256, 0, stream>>>(stateb, ln_b16, action_ids, fcwp, fc_b,
                                       out_W, out_b, (float*)d_out);
}

// Round 15
// 340.183 us; speedup vs baseline: 1.0193x; 1.0193x over previous
//
#include <hip/hip_runtime.h>
#include <hip/hip_bf16.h>
#include <stdint.h>

// Problem constants
#define NB 8192     // B
#define NL 16       // L
#define NS 256      // S
#define NT 1000     // T
#define NC 500      // C
#define NS5 1280    // 5*S
#define NROWS_JC (NB*15)   // 122880 join rows / inputx rows

typedef __attribute__((ext_vector_type(8))) short bf16x8;
typedef __attribute__((ext_vector_type(4))) float f32x4;

typedef __attribute__((address_space(1))) const void gas_void;
typedef __attribute__((address_space(3))) void las_void;

__device__ __forceinline__ void g2l16(const void* g, void* l) {
  __builtin_amdgcn_global_load_lds((gas_void*)g, (las_void*)l, 16, 0, 0);
}

__device__ __forceinline__ float sigf(float x) { return 1.f / (1.f + __expf(-x)); }
__device__ __forceinline__ float tanhfast(float x) {
  float e = __expf(2.f * fabsf(x));
  float t = 1.f - 2.f / (e + 1.f);
  return copysignf(t, x);
}
__device__ __forceinline__ unsigned short bf16b(float x) {
  __hip_bfloat16 h = __float2bfloat16(x);
  return *reinterpret_cast<unsigned short*>(&h);
}
__device__ __forceinline__ float b2f(unsigned short v) {
  union { unsigned u; float f; } x;
  x.u = (unsigned)v << 16;
  return x.f;
}

// Gate-interleaved packed-column decode, 5-gate.
__device__ __forceinline__ int origcol(int slice, int nc) {
  int q = nc / 80, rem = nc % 80;
  int g = rem / 16, u16 = rem % 16;
  int U = slice * 64 + q * 16 + u16;
  return g * 256 + U;
}
// 3-gate variant (level 0: only a,i,o live; f1/f2 multiply c==0).
__device__ __forceinline__ int origcol3(int slice, int nc) {
  int q = nc / 48, rem = nc % 48;
  int g = rem / 16, u16 = rem % 16;
  int U = slice * 64 + q * 16 + u16;
  const int G[3] = {0, 1, 4};  // a, i, o
  return G[g] * 256 + U;
}

// ---------------- Fused prologue ----------------
#define PB_INPUTX (NROWS_JC / 8)          // 15360
#define PB_LN     (PB_INPUTX + NT)        // +1000
#define PB_W12    (PB_LN + 480)           // +480
#define PB_W12L0  (PB_W12 + 288)          // +288 (4*24*192*4/256)
#define PB_FCW    (PB_W12L0 + 64)         // +64
#define PB_TOTAL  (PB_FCW + 8)            // +8 (bias5: 5 blocks, bias3: 3)

__global__ __launch_bounds__(256) void prologue_kernel(
    const float* __restrict__ jc, const float* __restrict__ jcW,
    const float* __restrict__ jcb, unsigned short* __restrict__ inpx,
    const float* __restrict__ emb, const float* __restrict__ lng,
    const float* __restrict__ lnb, unsigned short* __restrict__ ob16,
    const float* __restrict__ W1, const float* __restrict__ W2,
    const float* __restrict__ W0, unsigned short* __restrict__ w12p,
    unsigned short* __restrict__ w12p0,
    const float* __restrict__ fcW, unsigned short* __restrict__ fcwp,
    const float* __restrict__ b1, const float* __restrict__ b2,
    const float* __restrict__ b0, float* __restrict__ bias_zp,
    float* __restrict__ bias_zp3) {
  __shared__ float rs[4], rs2[4];
  const int bid = blockIdx.x;
  const int tid = threadIdx.x;

  if (bid < PB_INPUTX) {
    // ---- inputx: sparse join (R9-proven single-bit gather, 2 rows/wave) ----
    int wv = tid >> 6, lane = tid & 63;
    size_t row0 = (size_t)bid * 8 + wv * 2;
    const float* jr0 = jc + row0 * NC;
    const float* jr1 = jc + (row0 + 1) * NC;
    float4 p0 = *(const float4*)(jr0 + lane * 4);
    float4 q0 = *(const float4*)(jr1 + lane * 4);
    float4 p1 = make_float4(0.f, 0.f, 0.f, 0.f);
    float4 q1 = make_float4(0.f, 0.f, 0.f, 0.f);
    if (lane < 61) {
      p1 = *(const float4*)(jr0 + 256 + lane * 4);
      q1 = *(const float4*)(jr1 + 256 + lane * 4);
    }
    const float4 jb = *(const float4*)(jcb + lane * 4);
    float a0 = jb.x, a1 = jb.y, a2 = jb.z, a3 = jb.w;
    float c0 = jb.x, c1 = jb.y, c2 = jb.z, c3 = jb.w;

#define GATHER_MASK(val, cbase, d0, d1, d2, d3)                       \
    {                                                                 \
      unsigned long long m = __ballot((val) != 0.f);                  \
      while (m) {                                                     \
        int l = __ffsll(m) - 1;                                       \
        m &= m - 1;                                                   \
        int c = (cbase) + l * 4;                                      \
        const float4 w = *(const float4*)(jcW + (size_t)c * NS + lane * 4); \
        d0 += w.x; d1 += w.y; d2 += w.z; d3 += w.w;                   \
      }                                                               \
    }
    GATHER_MASK(p0.x, 0, a0, a1, a2, a3) GATHER_MASK(p0.y, 1, a0, a1, a2, a3)
    GATHER_MASK(p0.z, 2, a0, a1, a2, a3) GATHER_MASK(p0.w, 3, a0, a1, a2, a3)
    GATHER_MASK(p1.x, 256, a0, a1, a2, a3) GATHER_MASK(p1.y, 257, a0, a1, a2, a3)
    GATHER_MASK(p1.z, 258, a0, a1, a2, a3) GATHER_MASK(p1.w, 259, a0, a1, a2, a3)
    GATHER_MASK(q0.x, 0, c0, c1, c2, c3) GATHER_MASK(q0.y, 1, c0, c1, c2, c3)
    GATHER_MASK(q0.z, 2, c0, c1, c2, c3) GATHER_MASK(q0.w, 3, c0, c1, c2, c3)
    GATHER_MASK(q1.x, 256, c0, c1, c2, c3) GATHER_MASK(q1.y, 257, c0, c1, c2, c3)
    GATHER_MASK(q1.z, 258, c0, c1, c2, c3) GATHER_MASK(q1.w, 259, c0, c1, c2, c3)
#undef GATHER_MASK

    ushort4 o;
    o.x = bf16b(a0); o.y = bf16b(a1); o.z = bf16b(a2); o.w = bf16b(a3);
    *(ushort4*)(inpx + row0 * NS + lane * 4) = o;
    o.x = bf16b(c0); o.y = bf16b(c1); o.z = bf16b(c2); o.w = bf16b(c3);
    *(ushort4*)(inpx + (row0 + 1) * NS + lane * 4) = o;
  } else if (bid < PB_LN) {
    // ---- ln: LayerNorm of the embedding table (bf16 out) ----
    int t = bid - PB_INPUTX;
    int i = tid;
    int lane = i & 63, wv = i >> 6;
    float x = emb[t * NS + i];
    float s = x, s2 = x * x;
    for (int o = 1; o < 64; o <<= 1) {
      s += __shfl_xor(s, o);
      s2 += __shfl_xor(s2, o);
    }
    if (lane == 0) { rs[wv] = s; rs2[wv] = s2; }
    __syncthreads();
    float S = rs[0] + rs[1] + rs[2] + rs[3];
    float S2 = rs2[0] + rs2[1] + rs2[2] + rs2[3];
    float mu = S * (1.f / NS);
    float var = S2 * (1.f / NS) - mu * mu;
    float y = (x - mu) * rsqrtf(var + 1e-5f) * lng[i] + lnb[i];
    ob16[t * NS + i] = bf16b(y);
  } else if (bid < PB_W12) {
    // ---- pack_w12 (5-gate) ----
    int e = (bid - PB_LN) * 256 + tid;  // < 122880
    int kg = e & 3;
    int r = e >> 2;
    int nc = r % 320; r /= 320;
    int kc = r % 24;
    int slice = r / 24;
    int oc = origcol(slice, nc);
    int kbase = kc * 32 + kg * 8;
    unsigned short tmp[8];
#pragma unroll
    for (int j = 0; j < 8; ++j) {
      int k = kbase + j;
      float x;
      if (k < 256) x = W1[(size_t)k * NS5 + oc];
      else if (k < 512) x = W2[(size_t)(k - 256) * NS5 + oc];
      else x = W0[(size_t)(k - 512) * NS5 + oc];
      tmp[j] = bf16b(x);
    }
    ushort4 v0 = make_ushort4(tmp[0], tmp[1], tmp[2], tmp[3]);
    ushort4 v1 = make_ushort4(tmp[4], tmp[5], tmp[6], tmp[7]);
    size_t dst = (size_t)(slice * 24 + kc) * 20480 + (size_t)nc * 64 + kg * 16;
    *(ushort4*)((char*)w12p + dst) = v0;
    *(ushort4*)((char*)w12p + dst + 8) = v1;
  } else if (bid < PB_W12L0) {
    // ---- pack_w12_l0 (3-gate a,i,o) ----
    int e = (bid - PB_W12) * 256 + tid;  // < 73728
    int kg = e & 3;
    int r = e >> 2;
    int nc = r % 192; r /= 192;
    int kc = r % 24;
    int slice = r / 24;
    int oc = origcol3(slice, nc);
    int kbase = kc * 32 + kg * 8;
    unsigned short tmp[8];
#pragma unroll
    for (int j = 0; j < 8; ++j) {
      int k = kbase + j;
      float x;
      if (k < 256) x = W1[(size_t)k * NS5 + oc];
      else if (k < 512) x = W2[(size_t)(k - 256) * NS5 + oc];
      else x = W0[(size_t)(k - 512) * NS5 + oc];
      tmp[j] = bf16b(x);
    }
    ushort4 v0 = make_ushort4(tmp[0], tmp[1], tmp[2], tmp[3]);
    ushort4 v1 = make_ushort4(tmp[4], tmp[5], tmp[6], tmp[7]);
    size_t dst = (size_t)(slice * 24 + kc) * 12288 + (size_t)nc * 64 + kg * 16;
    *(ushort4*)((char*)w12p0 + dst) = v0;
    *(ushort4*)((char*)w12p0 + dst + 8) = v1;
  } else if (bid < PB_FCW) {
    // ---- pack_fcw ----
    int e = (bid - PB_W12L0) * 256 + tid;  // < 16384
    int kg = e & 3;
    int r = e >> 2;
    int nc = r & 255;
    int kc = r >> 8;
    int kbase = kc * 32 + kg * 8;
    unsigned short tmp[8];
#pragma unroll
    for (int j = 0; j < 8; ++j) tmp[j] = bf16b(fcW[(size_t)(kbase + j) * NS + nc]);
    ushort4 v0 = make_ushort4(tmp[0], tmp[1], tmp[2], tmp[3]);
    ushort4 v1 = make_ushort4(tmp[4], tmp[5], tmp[6], tmp[7]);
    size_t dst = (size_t)kc * 16384 + (size_t)nc * 64 + kg * 16;
    *(ushort4*)((char*)fcwp + dst) = v0;
    *(ushort4*)((char*)fcwp + dst + 8) = v1;
  } else if (bid < PB_FCW + 5) {
    // ---- bias5 ----
    int pc = (bid - PB_FCW) * 256 + tid;
    if (pc < NS5) {
      int slice = pc / 320, nc = pc % 320;
      int oc = origcol(slice, nc);
      bias_zp[pc] = b1[oc] + b2[oc] + b0[oc];
    }
  } else {
    // ---- bias3 ----
    int pc = (bid - PB_FCW - 5) * 256 + tid;
    if (pc < 768) {
      int slice = pc / 192, nc = pc % 192;
      int oc = origcol3(slice, nc);
      bias_zp3[pc] = b1[oc] + b2[oc] + b0[oc];
    }
  }
}

// ---------------- Level 0: 128-row x 3-gate, R12-structure macro form ------
// Same pipeline as the proven 5-gate kernel (128-row tile, 2 blocks/CU,
// rotating reg-B prefetch, pinned VMEM order), just 3 gates (a,i,o) since
// c==0 kills f1/f2.  acc[8][3]=96 AGPR.  B-L2 traffic/CU-kc: 40->24KB.
__global__ __launch_bounds__(256, 2) void level0_kernel(
    const unsigned short* __restrict__ h_in,  // ln_b16 table
    const unsigned short* __restrict__ inpx,  // (B*15,256) bf16
    const unsigned short* __restrict__ w12p0, // 3-gate packed images
    const float* __restrict__ bias_zp3,       // (768)
    unsigned short* __restrict__ h_out,       // (65536,256) bf16
    unsigned* __restrict__ c_out,             // (32768,256) u32 pairs
    const int* __restrict__ leaf) {
  __shared__ __align__(1024) char ldsA[2 * 16384];
  const int tid = threadIdx.x, lane = tid & 63, wv = tid >> 6;
  const int m0 = blockIdx.x * 128;
  const int slice = blockIdx.y;

  f32x4 acc[8][3];
#pragma unroll
  for (int a = 0; a < 8; ++a)
#pragma unroll
    for (int t = 0; t < 3; ++t) acc[a][t] = (f32x4){0.f, 0.f, 0.f, 0.f};

  const int rl64 = wv * 16 + (lane >> 2);
  const int ss = (lane & 3) ^ ((rl64 >> 1) & 3);
  const int mlo = m0 + rl64, mhi = mlo + 64;
  const char* h0lo = (const char*)h_in + ((size_t)leaf[2 * mlo] * 512 + (size_t)ss * 16);
  const char* h1lo = (const char*)h_in + ((size_t)leaf[2 * mlo + 1] * 512 + (size_t)ss * 16);
  const char* h0hi = (const char*)h_in + ((size_t)leaf[2 * mhi] * 512 + (size_t)ss * 16);
  const char* h1hi = (const char*)h_in + ((size_t)leaf[2 * mhi + 1] * 512 + (size_t)ss * 16);
  // L0: log2n=3, joff=0
  const char* xlo = (const char*)inpx +
      (((size_t)(mlo >> 3) * 15 + (mlo & 7)) * 512 + (size_t)ss * 16);
  const char* xhi = (const char*)inpx +
      (((size_t)(mhi >> 3) * 15 + (mhi & 7)) * 512 + (size_t)ss * 16);
  char* adst = ldsA + wv * 1024;

  auto srcA = [&](int kc, int j) -> const char* {
    const char* h0 = j ? h0hi : h0lo;
    const char* h1 = j ? h1hi : h1lo;
    const char* xs = j ? xhi : xlo;
    return (kc < 8) ? h0 + kc * 64
         : (kc < 16) ? h1 + (kc - 8) * 64
                     : xs + (kc - 16) * 64;
  };
  auto stageA = [&](int kt, int buf) {
    char* db = adst + buf * 16384;
    g2l16(srcA(2 * kt, 0), db);
    g2l16(srcA(2 * kt, 1), db + 4096);
    g2l16(srcA(2 * kt + 1, 0), db + 8192);
    g2l16(srcA(2 * kt + 1, 1), db + 12288);
  };

  const int aoff = (lane & 15) * 64 + (((lane >> 4) ^ ((lane >> 1) & 3)) << 4);
  const char* gB = (const char*)w12p0 + (size_t)slice * 24 * 12288 +
                   (size_t)(wv * 48 + (lane & 15)) * 64 + (size_t)(lane >> 4) * 16;

  bf16x8 bcur[3], bnxt[3];
  auto loadB = [&](int kc, bf16x8* dst) {
    const char* gk = gB + (size_t)kc * 12288;
    dst[0] = *(const bf16x8*)(gk);
    dst[1] = *(const bf16x8*)(gk + 1024);
    dst[2] = *(const bf16x8*)(gk + 2048);
  };

#define CLUSTER0(pA, bset)                                                          \
  {                                                                                 \
    bf16x8 a0 = *(const bf16x8*)(pA);                                               \
    bf16x8 a1 = *(const bf16x8*)((pA) + 1024);                                      \
    bf16x8 a2 = *(const bf16x8*)((pA) + 2048);                                      \
    bf16x8 a3 = *(const bf16x8*)((pA) + 3072);                                      \
    bf16x8 a4 = *(const bf16x8*)((pA) + 4096);                                      \
    bf16x8 a5 = *(const bf16x8*)((pA) + 5120);                                      \
    bf16x8 a6 = *(const bf16x8*)((pA) + 6144);                                      \
    bf16x8 a7 = *(const bf16x8*)((pA) + 7168);                                      \
    _Pragma("unroll")                                                               \
    for (int g = 0; g < 3; ++g) {                                                   \
      acc[0][g] = __builtin_amdgcn_mfma_f32_16x16x32_bf16(a0, bset[g], acc[0][g], 0, 0, 0); \
      acc[1][g] = __builtin_amdgcn_mfma_f32_16x16x32_bf16(a1, bset[g], acc[1][g], 0, 0, 0); \
      acc[2][g] = __builtin_amdgcn_mfma_f32_16x16x32_bf16(a2, bset[g], acc[2][g], 0, 0, 0); \
      acc[3][g] = __builtin_amdgcn_mfma_f32_16x16x32_bf16(a3, bset[g], acc[3][g], 0, 0, 0); \
      acc[4][g] = __builtin_amdgcn_mfma_f32_16x16x32_bf16(a4, bset[g], acc[4][g], 0, 0, 0); \
      acc[5][g] = __builtin_amdgcn_mfma_f32_16x16x32_bf16(a5, bset[g], acc[5][g], 0, 0, 0); \
      acc[6][g] = __builtin_amdgcn_mfma_f32_16x16x32_bf16(a6, bset[g], acc[6][g], 0, 0, 0); \
      acc[7][g] = __builtin_amdgcn_mfma_f32_16x16x32_bf16(a7, bset[g], acc[7][g], 0, 0, 0); \
    }                                                                               \
  }

  stageA(0, 0);
  loadB(0, bcur);
  asm volatile("s_waitcnt vmcnt(0)" ::: "memory");
  __builtin_amdgcn_s_barrier();

  for (int kt = 0; kt < 12; ++kt) {
    const int buf = kt & 1;
    stageA(kt < 11 ? kt + 1 : 11, buf ^ 1);
    __builtin_amdgcn_sched_barrier(0);
    loadB(2 * kt + 1, bnxt);
    const char* pA = ldsA + buf * 16384 + aoff;
    CLUSTER0(pA, bcur);
    loadB(2 * kt + 2 < 24 ? 2 * kt + 2 : 0, bcur);
    CLUSTER0(pA + 8192, bnxt);
    __builtin_amdgcn_sched_barrier(0);
    asm volatile("s_waitcnt vmcnt(3)" ::: "memory");
    __builtin_amdgcn_sched_barrier(0);
    __builtin_amdgcn_s_barrier();
  }
#undef CLUSTER0

  // ---- Epilogue: c==0 cell ----
  float bias[3];
#pragma unroll
  for (int g = 0; g < 3; ++g)
    bias[g] = bias_zp3[slice * 192 + wv * 48 + g * 16 + (lane & 15)];
  const int u = slice * 64 + wv * 16 + (lane & 15);

#pragma unroll
  for (int rt = 0; rt < 8; ++rt) {
    const int base = m0 + rt * 16 + (lane >> 4) * 4;
    float hv[4], cv[4];
#pragma unroll
    for (int r = 0; r < 4; ++r) {
      float za = acc[rt][0][r] + bias[0];
      float zi = acc[rt][1][r] + bias[1];
      float zo = acc[rt][2][r] + bias[2];
      float cnew = tanhfast(za) * sigf(zi);
      cv[r] = cnew;
      hv[r] = sigf(zo) * tanhfast(cnew);
    }
#pragma unroll
    for (int r = 0; r < 4; ++r)
      h_out[(size_t)(base + r) * NS + u] = bf16b(hv[r]);
    const size_t pb = (size_t)(base >> 1) * NS + u;
    c_out[pb] = (unsigned)bf16b(cv[0]) | ((unsigned)bf16b(cv[1]) << 16);
    c_out[pb + NS] = (unsigned)bf16b(cv[2]) | ((unsigned)bf16b(cv[3]) << 16);
  }
}

// ---------------- Fused tree-level GEMM + LSTM cell (5-gate, R12-exact) ----
template <bool FIRST, bool LAST>
__global__ __launch_bounds__(256, 2) void level_kernel(
    const unsigned short* __restrict__ h_in,
    const unsigned* __restrict__ c_in,        // (M,256) u32 pairs
    const unsigned short* __restrict__ inpx,
    const unsigned short* __restrict__ w12p,
    const float* __restrict__ bias_zp,
    unsigned short* __restrict__ h_out,
    unsigned* __restrict__ c_out,
    unsigned short* __restrict__ state_out,
    const int* __restrict__ leaf,
    int log2n, int joff) {
  __shared__ __align__(1024) char ldsA[2 * 16384];
  const int tid = threadIdx.x, lane = tid & 63, wv = tid >> 6;
  const int m0 = blockIdx.x * 128;
  const int slice = blockIdx.y;
  const int n = 1 << log2n;

  f32x4 acc[8][5];
#pragma unroll
  for (int a = 0; a < 8; ++a)
#pragma unroll
    for (int t = 0; t < 5; ++t) acc[a][t] = (f32x4){0.f, 0.f, 0.f, 0.f};

  const int rl64 = wv * 16 + (lane >> 2);
  const int ss = (lane & 3) ^ ((rl64 >> 1) & 3);
  const int mlo = m0 + rl64, mhi = mlo + 64;
  const char* h0lo; const char* h1lo; const char* h0hi; const char* h1hi;
  if (FIRST) {
    h0lo = (const char*)h_in + ((size_t)leaf[2 * mlo] * 512 + (size_t)ss * 16);
    h1lo = (const char*)h_in + ((size_t)leaf[2 * mlo + 1] * 512 + (size_t)ss * 16);
    h0hi = (const char*)h_in + ((size_t)leaf[2 * mhi] * 512 + (size_t)ss * 16);
    h1hi = (const char*)h_in + ((size_t)leaf[2 * mhi + 1] * 512 + (size_t)ss * 16);
  } else {
    h0lo = (const char*)h_in + ((size_t)mlo * 1024 + (size_t)ss * 16);
    h1lo = h0lo;
    h0hi = (const char*)h_in + ((size_t)mhi * 1024 + (size_t)ss * 16);
    h1hi = h0hi;
  }
  const char* xlo = (const char*)inpx +
      (((size_t)(mlo >> log2n) * 15 + joff + (mlo & (n - 1))) * 512 + (size_t)ss * 16);
  const char* xhi = (const char*)inpx +
      (((size_t)(mhi >> log2n) * 15 + joff + (mhi & (n - 1))) * 512 + (size_t)ss * 16);
  char* adst = ldsA + wv * 1024;

  auto srcA = [&](int kc, int j) -> const char* {
    const char* h0 = j ? h0hi : h0lo;
    const char* h1 = j ? h1hi : h1lo;
    const char* xs = j ? xhi : xlo;
    if (FIRST) {
      return (kc < 8) ? h0 + kc * 64
           : (kc < 16) ? h1 + (kc - 8) * 64
                       : xs + (kc - 16) * 64;
    }
    return (kc < 16) ? h0 + kc * 64 : xs + (kc - 16) * 64;
  };
  auto stageA = [&](int kt, int buf) {
    char* db = adst + buf * 16384;
    g2l16(srcA(2 * kt, 0), db);
    g2l16(srcA(2 * kt, 1), db + 4096);
    g2l16(srcA(2 * kt + 1, 0), db + 8192);
    g2l16(srcA(2 * kt + 1, 1), db + 12288);
  };

  const int aoff = (lane & 15) * 64 + (((lane >> 4) ^ ((lane >> 1) & 3)) << 4);
  const char* gB = (const char*)w12p + (size_t)slice * 24 * 20480 +
                   (size_t)(wv * 80 + (lane & 15)) * 64 + (size_t)(lane >> 4) * 16;

  bf16x8 bcur[5], bnxt[5];
  auto loadB = [&](int kc, bf16x8* dst) {
    const char* gk = gB + (size_t)kc * 20480;
#pragma unroll
    for (int g = 0; g < 5; ++g) dst[g] = *(const bf16x8*)(gk + g * 1024);
  };

#define CLUSTER(pA, bset)                                                           \
  {                                                                                 \
    bf16x8 a0 = *(const bf16x8*)(pA);                                               \
    bf16x8 a1 = *(const bf16x8*)((pA) + 1024);                                      \
    bf16x8 a2 = *(const bf16x8*)((pA) + 2048);                                      \
    bf16x8 a3 = *(const bf16x8*)((pA) + 3072);                                      \
    bf16x8 a4 = *(const bf16x8*)((pA) + 4096);                                      \
    bf16x8 a5 = *(const bf16x8*)((pA) + 5120);                                      \
    bf16x8 a6 = *(const bf16x8*)((pA) + 6144);                                      \
    bf16x8 a7 = *(const bf16x8*)((pA) + 7168);                                      \
    _Pragma("unroll")                                                               \
    for (int g = 0; g < 5; ++g) {                                                   \
      acc[0][g] = __builtin_amdgcn_mfma_f32_16x16x32_bf16(a0, bset[g], acc[0][g], 0, 0, 0); \
      acc[1][g] = __builtin_amdgcn_mfma_f32_16x16x32_bf16(a1, bset[g], acc[1][g], 0, 0, 0); \
      acc[2][g] = __builtin_amdgcn_mfma_f32_16x16x32_bf16(a2, bset[g], acc[2][g], 0, 0, 0); \
      acc[3][g] = __builtin_amdgcn_mfma_f32_16x16x32_bf16(a3, bset[g], acc[3][g], 0, 0, 0); \
      acc[4][g] = __builtin_amdgcn_mfma_f32_16x16x32_bf16(a4, bset[g], acc[4][g], 0, 0, 0); \
      acc[5][g] = __builtin_amdgcn_mfma_f32_16x16x32_bf16(a5, bset[g], acc[5][g], 0, 0, 0); \
      acc[6][g] = __builtin_amdgcn_mfma_f32_16x16x32_bf16(a6, bset[g], acc[6][g], 0, 0, 0); \
      acc[7][g] = __builtin_amdgcn_mfma_f32_16x16x32_bf16(a7, bset[g], acc[7][g], 0, 0, 0); \
    }                                                                               \
  }

  stageA(0, 0);
  loadB(0, bcur);
  asm volatile("s_waitcnt vmcnt(0)" ::: "memory");
  __builtin_amdgcn_s_barrier();

  for (int kt = 0; kt < 12; ++kt) {
    const int buf = kt & 1;
    stageA(kt < 11 ? kt + 1 : 11, buf ^ 1);
    __builtin_amdgcn_sched_barrier(0);
    loadB(2 * kt + 1, bnxt);
    const char* pA = ldsA + buf * 16384 + aoff;
    CLUSTER(pA, bcur);
    loadB(2 * kt + 2 < 24 ? 2 * kt + 2 : 0, bcur);
    CLUSTER(pA + 8192, bnxt);
    __builtin_amdgcn_sched_barrier(0);
    asm volatile("s_waitcnt vmcnt(5)" ::: "memory");
    __builtin_amdgcn_sched_barrier(0);
    __builtin_amdgcn_s_barrier();
  }
#undef CLUSTER

  float bias[5];
#pragma unroll
  for (int g = 0; g < 5; ++g)
    bias[g] = bias_zp[slice * 320 + wv * 80 + g * 16 + (lane & 15)];
  const int u = slice * 64 + wv * 16 + (lane & 15);

#pragma unroll
  for (int rt = 0; rt < 8; ++rt) {
    const int base = m0 + rt * 16 + (lane >> 4) * 4;
    float hv[4], cv[4];
#pragma unroll
    for (int r = 0; r < 4; ++r) {
      int row = base + r;
      float za = acc[rt][0][r] + bias[0];
      float zi = acc[rt][1][r] + bias[1];
      float zo = acc[rt][4][r] + bias[4];
      float cnew = tanhfast(za) * sigf(zi);
      if (!FIRST) {
        float zf1 = acc[rt][2][r] + bias[2];
        float zf2 = acc[rt][3][r] + bias[3];
        unsigned pc = c_in[(size_t)row * NS + u];
        float cl = b2f((unsigned short)(pc & 0xffff));
        float cr = b2f((unsigned short)(pc >> 16));
        cnew += sigf(zf1) * cl + sigf(zf2) * cr;
      }
      cv[r] = cnew;
      hv[r] = sigf(zo) * tanhfast(cnew);
    }
    if (LAST) {
#pragma unroll
      for (int r = 0; r < 4; ++r)
        state_out[(size_t)(base + r) * NS + u] = bf16b(hv[r]);
    } else {
#pragma unroll
      for (int r = 0; r < 4; ++r)
        h_out[(size_t)(base + r) * NS + u] = bf16b(hv[r]);
      const size_t pb = (size_t)(base >> 1) * NS + u;
      c_out[pb] = (unsigned)bf16b(cv[0]) | ((unsigned)bf16b(cv[1]) << 16);
      c_out[pb + NS] = (unsigned)bf16b(cv[2]) | ((unsigned)bf16b(cv[3]) << 16);
    }
  }
}

// ---------------- Final head via MFMA ----------------
__global__ __launch_bounds__(256, 2) void fc_mfma(
    const unsigned short* __restrict__ stateb,
    const unsigned short* __restrict__ ln_b16,
    const int* __restrict__ action_ids, const unsigned short* __restrict__ fcwp,
    const float* __restrict__ fcb, const float* __restrict__ outW,
    const float* __restrict__ outb, float* __restrict__ out) {
  __shared__ __align__(1024) char ldsA[2 * 8192];
  __shared__ float red[64][4];
  const int tid = threadIdx.x, lane = tid & 63, wv = tid >> 6;
  const int m0 = blockIdx.x * 64;

  f32x4 acc[4][4];
#pragma unroll
  for (int a = 0; a < 4; ++a)
#pragma unroll
    for (int t = 0; t < 4; ++t) acc[a][t] = (f32x4){0.f, 0.f, 0.f, 0.f};

  const int rl = wv * 16 + (lane >> 2);
  const int ss = (lane & 3) ^ ((rl >> 1) & 3);
  const int m = m0 + rl;
  const char* src0 = (const char*)stateb + ((size_t)m * 512 + (size_t)ss * 16);
  const char* src1 =
      (const char*)ln_b16 + ((size_t)action_ids[m] * 512 + (size_t)ss * 16);
  char* adst = ldsA + wv * 1024;

  auto srcA = [&](int kc) -> const char* {
    return (kc < 8) ? src0 + kc * 64 : src1 + (kc - 8) * 64;
  };
  auto stageA = [&](int kt, int buf) {
    g2l16(srcA(2 * kt), adst + buf * 8192);
    g2l16(srcA(2 * kt + 1), adst + buf * 8192 + 4096);
  };

  const int aoff = (lane & 15) * 64 + (((lane >> 4) ^ ((lane >> 1) & 3)) << 4);
  const char* gB = (const char*)fcwp +
                   (size_t)(wv * 64 + (lane & 15)) * 64 + (size_t)(lane >> 4) * 16;

  bf16x8 bcur[4], bnxt[4];
  auto loadB = [&](int kc, bf16x8* dst) {
    const char* gk = gB + (size_t)kc * 16384;
#pragma unroll
    for (int t = 0; t < 4; ++t) dst[t] = *(const bf16x8*)(gk + t * 1024);
  };

  stageA(0, 0);
  loadB(0, bcur);
  asm volatile("s_waitcnt vmcnt(0)" ::: "memory");
  __builtin_amdgcn_s_barrier();

  for (int kt = 0; kt < 8; ++kt) {
    const int buf = kt & 1;
    stageA(kt < 7 ? kt + 1 : 7, buf ^ 1);
    __builtin_amdgcn_sched_barrier(0);
    loadB(2 * kt + 1, bnxt);
    const char* pA = ldsA + buf * 8192 + aoff;
    bf16x8 a0 = *(const bf16x8*)(pA);
    bf16x8 a1 = *(const bf16x8*)(pA + 1024);
    bf16x8 a2 = *(const bf16x8*)(pA + 2048);
    bf16x8 a3 = *(const bf16x8*)(pA + 3072);
#pragma unroll
    for (int t = 0; t < 4; ++t) {
      acc[0][t] = __builtin_amdgcn_mfma_f32_16x16x32_bf16(a0, bcur[t], acc[0][t], 0, 0, 0);
      acc[1][t] = __builtin_amdgcn_mfma_f32_16x16x32_bf16(a1, bcur[t], acc[1][t], 0, 0, 0);
      acc[2][t] = __builtin_amdgcn_mfma_f32_16x16x32_bf16(a2, bcur[t], acc[2][t], 0, 0, 0);
      acc[3][t] = __builtin_amdgcn_mfma_f32_16x16x32_bf16(a3, bcur[t], acc[3][t], 0, 0, 0);
    }
    loadB(2 * kt + 2 < 16 ? 2 * kt + 2 : 0, bcur);
    bf16x8 c0 = *(const bf16x8*)(pA + 4096);
    bf16x8 c1 = *(const bf16x8*)(pA + 5120);
    bf16x8 c2 = *(const bf16x8*)(pA + 6144);
    bf16x8 c3 = *(const bf16x8*)(pA + 7168);
#pragma unroll
    for (int t = 0; t < 4; ++t) {
      acc[0][t] = __builtin_amdgcn_mfma_f32_16x16x32_bf16(c0, bnxt[t], acc[0][t], 0, 0, 0);
      acc[1][t] = __builtin_amdgcn_mfma_f32_16x16x32_bf16(c1, bnxt[t], acc[1][t], 0, 0, 0);
      acc[2][t] = __builtin_amdgcn_mfma_f32_16x16x32_bf16(c2, bnxt[t], acc[2][t], 0, 0, 0);
      acc[3][t] = __builtin_amdgcn_mfma_f32_16x16x32_bf16(c3, bnxt[t], acc[3][t], 0, 0, 0);
    }
    __builtin_amdgcn_sched_barrier(0);
    asm volatile("s_waitcnt vmcnt(4)" ::: "memory");
    __builtin_amdgcn_sched_barrier(0);
    __builtin_amdgcn_s_barrier();
  }

  float fb[4], ow[4];
#pragma unroll
  for (int t = 0; t < 4; ++t) {
    int col = wv * 64 + t * 16 + (lane & 15);
    fb[t] = fcb[col];
    ow[t] = outW[col];
  }
#pragma unroll
  for (int rt = 0; rt < 4; ++rt) {
#pragma unroll
    for (int r = 0; r < 4; ++r) {
      float s = 0.f;
#pragma unroll
      for (int t = 0; t < 4; ++t)
        s += fmaxf(acc[rt][t][r] + fb[t], 0.f) * ow[t];
      s += __shfl_xor(s, 1);
      s += __shfl_xor(s, 2);
      s += __shfl_xor(s, 4);
      s += __shfl_xor(s, 8);
      if ((lane & 15) == 0) red[rt * 16 + (lane >> 4) * 4 + r][wv] = s;
    }
  }
  __syncthreads();
  if (tid < 64)
    out[m0 + tid] = red[tid][0] + red[tid][1] + red[tid][2] + red[tid][3] + outb[0];
}

extern "C" void kernel_launch(void* const* d_in, const int* in_sizes, int n_in,
                              void* d_out, int out_size, void* d_ws, size_t ws_size,
                              hipStream_t stream) {
  const int* leaf_ids = (const int*)d_in[0];
  const int* action_ids = (const int*)d_in[1];
  const float* join_cols = (const float*)d_in[2];
  const float* emb = (const float*)d_in[3];
  const float* ln_g = (const float*)d_in[4];
  const float* ln_b = (const float*)d_in[5];
  const float* jc_W = (const float*)d_in[6];
  const float* jc_b = (const float*)d_in[7];
  const float* W1 = (const float*)d_in[8];
  const float* b1 = (const float*)d_in[9];
  const float* W2 = (const float*)d_in[10];
  const float* b2 = (const float*)d_in[11];
  const float* W0 = (const float*)d_in[12];
  const float* b0 = (const float*)d_in[13];
  const float* fc_W = (const float*)d_in[14];
  const float* fc_b = (const float*)d_in[15];
  const float* out_W = (const float*)d_in[16];
  const float* out_b = (const float*)d_in[17];

  char* ws = (char*)d_ws;
  size_t o = 0;
  auto alloc = [&](size_t bytes) {
    size_t r = o;
    o += (bytes + 255) & ~(size_t)255;
    return r;
  };
  unsigned short* ln_b16 = (unsigned short*)(ws + alloc((size_t)NT * NS * 2));
  unsigned short* w12p = (unsigned short*)(ws + alloc((size_t)4 * 24 * 20480));
  unsigned short* w12p0 = (unsigned short*)(ws + alloc((size_t)4 * 24 * 12288));
  unsigned short* fcwp = (unsigned short*)(ws + alloc((size_t)16 * 16384));
  float* bias_zp = (float*)(ws + alloc((size_t)NS5 * 4));
  float* bias_zp3 = (float*)(ws + alloc((size_t)768 * 4));
  unsigned short* inpx = (unsigned short*)(ws + alloc((size_t)NROWS_JC * NS * 2));
  unsigned short* hX = (unsigned short*)(ws + alloc((size_t)NB * 8 * NS * 2));
  unsigned short* hY = (unsigned short*)(ws + alloc((size_t)NB * 4 * NS * 2));
  unsigned* cX = (unsigned*)(ws + alloc((size_t)NB * 8 * NS * 2));
  unsigned* cY = (unsigned*)(ws + alloc((size_t)NB * 4 * NS * 2));
  unsigned short* stateb = (unsigned short*)(ws + alloc((size_t)NB * NS * 2));
  (void)ws_size; (void)in_sizes; (void)n_in; (void)out_size;

  // Fused prologue
  prologue_kernel<<<PB_TOTAL, 256, 0, stream>>>(
      join_cols, jc_W, jc_b, inpx, emb, ln_g, ln_b, ln_b16, W1, W2, W0, w12p,
      w12p0, fc_W, fcwp, b1, b2, b0, bias_zp, bias_zp3);

  // Level 0: 128-row x 3-gate (R12 structure), M=65536
  level0_kernel<<<dim3(512, 4), 256, 0, stream>>>(
      ln_b16, inpx, w12p0, bias_zp3, hX, cX, leaf_ids);
  // Level 1: n=4, off=8, M=32768
  level_kernel<false, false><<<dim3(256, 4), 256, 0, stream>>>(
      hX, cX, inpx, w12p, bias_zp, hY, cY, nullptr, leaf_ids, 2, 8);
  // Level 2: n=2, off=12, M=16384
  level_kernel<false, false><<<dim3(128, 4), 256, 0, stream>>>(
      hY, cY, inpx, w12p, bias_zp, hX, cX, nullptr, leaf_ids, 1, 12);
  // Level 3: n=1, off=14, M=8192 -> state bf16
  level_kernel<false, true><<<dim3(64, 4), 256, 0, stream>>>(
      hX, cX, inpx, w12p, bias_zp, nullptr, nullptr, stateb, leaf_ids, 0, 14);

  fc_mfma<<<NB / 64, 256, 0, stream>>>(stateb, ln_b16, action_ids, fcwp, fc_b,
                                       out_W, out_b, (float*)d_out);
}

// Round 16
// 332.555 us; speedup vs baseline: 1.0427x; 1.0229x over previous
//
#include <hip/hip_runtime.h>
#include <hip/hip_bf16.h>
#include <stdint.h>

// Problem constants
#define NB 8192     // B
#define NL 16       // L
#define NS 256      // S
#define NT 1000     // T
#define NC 500      // C
#define NS5 1280    // 5*S
#define NROWS_JC (NB*15)   // 122880 join rows / inputx rows

typedef __attribute__((ext_vector_type(8))) short bf16x8;
typedef __attribute__((ext_vector_type(4))) float f32x4;

typedef __attribute__((address_space(1))) const void gas_void;
typedef __attribute__((address_space(3))) void las_void;

__device__ __forceinline__ void g2l16(const void* g, void* l) {
  __builtin_amdgcn_global_load_lds((gas_void*)g, (las_void*)l, 16, 0, 0);
}

__device__ __forceinline__ float sigf(float x) { return 1.f / (1.f + __expf(-x)); }
__device__ __forceinline__ float tanhfast(float x) {
  float e = __expf(2.f * fabsf(x));
  float t = 1.f - 2.f / (e + 1.f);
  return copysignf(t, x);
}
__device__ __forceinline__ unsigned short bf16b(float x) {
  __hip_bfloat16 h = __float2bfloat16(x);
  return *reinterpret_cast<unsigned short*>(&h);
}
__device__ __forceinline__ float b2f(unsigned short v) {
  union { unsigned u; float f; } x;
  x.u = (unsigned)v << 16;
  return x.f;
}

// Gate-interleaved packed-column decode (quarter-based so each col-wave is
// gate-complete for 16 units).
__device__ __forceinline__ int origcol(int slice, int nc) {
  int q = nc / 80, rem = nc % 80;
  int g = rem / 16, u16 = rem % 16;
  int U = slice * 64 + q * 16 + u16;
  return g * 256 + U;
}

// ---------------- Fused prologue ----------------
// Five independent prep kernels in one dispatch, inputx blocks first so the
// small ones (ln / pack_w12 / pack_fcw / bias, ~15-18us serial) hide under
// inputx's ~55us HBM scan instead of running back-to-back before it.
#define PB_INPUTX (NROWS_JC / 8)          // 15360
#define PB_LN     (PB_INPUTX + NT)        // +1000
#define PB_W12    (PB_LN + 480)           // +480
#define PB_FCW    (PB_W12 + 64)           // +64
#define PB_TOTAL  (PB_FCW + 5)            // +5 (bias)

__global__ __launch_bounds__(256) void prologue_kernel(
    const float* __restrict__ jc, const float* __restrict__ jcW,
    const float* __restrict__ jcb, unsigned short* __restrict__ inpx,
    const float* __restrict__ emb, const float* __restrict__ lng,
    const float* __restrict__ lnb, unsigned short* __restrict__ ob16,
    const float* __restrict__ W1, const float* __restrict__ W2,
    const float* __restrict__ W0, unsigned short* __restrict__ w12p,
    const float* __restrict__ fcW, unsigned short* __restrict__ fcwp,
    const float* __restrict__ b1, const float* __restrict__ b2,
    const float* __restrict__ b0, float* __restrict__ bias_zp) {
  __shared__ float rs[4], rs2[4];
  const int bid = blockIdx.x;
  const int tid = threadIdx.x;

  if (bid < PB_INPUTX) {
    // ---- inputx: sparse join (R9-proven single-bit gather, 2 rows/wave) ----
    int wv = tid >> 6, lane = tid & 63;
    size_t row0 = (size_t)bid * 8 + wv * 2;
    const float* jr0 = jc + row0 * NC;
    const float* jr1 = jc + (row0 + 1) * NC;
    float4 p0 = *(const float4*)(jr0 + lane * 4);
    float4 q0 = *(const float4*)(jr1 + lane * 4);
    float4 p1 = make_float4(0.f, 0.f, 0.f, 0.f);
    float4 q1 = make_float4(0.f, 0.f, 0.f, 0.f);
    if (lane < 61) {
      p1 = *(const float4*)(jr0 + 256 + lane * 4);
      q1 = *(const float4*)(jr1 + 256 + lane * 4);
    }
    const float4 jb = *(const float4*)(jcb + lane * 4);
    float a0 = jb.x, a1 = jb.y, a2 = jb.z, a3 = jb.w;
    float c0 = jb.x, c1 = jb.y, c2 = jb.z, c3 = jb.w;

#define GATHER_MASK(val, cbase, d0, d1, d2, d3)                       \
    {                                                                 \
      unsigned long long m = __ballot((val) != 0.f);                  \
      while (m) {                                                     \
        int l = __ffsll(m) - 1;                                       \
        m &= m - 1;                                                   \
        int c = (cbase) + l * 4;                                      \
        const float4 w = *(const float4*)(jcW + (size_t)c * NS + lane * 4); \
        d0 += w.x; d1 += w.y; d2 += w.z; d3 += w.w;                   \
      }                                                               \
    }
    GATHER_MASK(p0.x, 0, a0, a1, a2, a3) GATHER_MASK(p0.y, 1, a0, a1, a2, a3)
    GATHER_MASK(p0.z, 2, a0, a1, a2, a3) GATHER_MASK(p0.w, 3, a0, a1, a2, a3)
    GATHER_MASK(p1.x, 256, a0, a1, a2, a3) GATHER_MASK(p1.y, 257, a0, a1, a2, a3)
    GATHER_MASK(p1.z, 258, a0, a1, a2, a3) GATHER_MASK(p1.w, 259, a0, a1, a2, a3)
    GATHER_MASK(q0.x, 0, c0, c1, c2, c3) GATHER_MASK(q0.y, 1, c0, c1, c2, c3)
    GATHER_MASK(q0.z, 2, c0, c1, c2, c3) GATHER_MASK(q0.w, 3, c0, c1, c2, c3)
    GATHER_MASK(q1.x, 256, c0, c1, c2, c3) GATHER_MASK(q1.y, 257, c0, c1, c2, c3)
    GATHER_MASK(q1.z, 258, c0, c1, c2, c3) GATHER_MASK(q1.w, 259, c0, c1, c2, c3)
#undef GATHER_MASK

    ushort4 o;
    o.x = bf16b(a0); o.y = bf16b(a1); o.z = bf16b(a2); o.w = bf16b(a3);
    *(ushort4*)(inpx + row0 * NS + lane * 4) = o;
    o.x = bf16b(c0); o.y = bf16b(c1); o.z = bf16b(c2); o.w = bf16b(c3);
    *(ushort4*)(inpx + (row0 + 1) * NS + lane * 4) = o;
  } else if (bid < PB_LN) {
    // ---- ln: LayerNorm of the embedding table (bf16 out) ----
    int t = bid - PB_INPUTX;
    int i = tid;
    int lane = i & 63, wv = i >> 6;
    float x = emb[t * NS + i];
    float s = x, s2 = x * x;
    for (int o = 1; o < 64; o <<= 1) {
      s += __shfl_xor(s, o);
      s2 += __shfl_xor(s2, o);
    }
    if (lane == 0) { rs[wv] = s; rs2[wv] = s2; }
    __syncthreads();
    float S = rs[0] + rs[1] + rs[2] + rs[3];
    float S2 = rs2[0] + rs2[1] + rs2[2] + rs2[3];
    float mu = S * (1.f / NS);
    float var = S2 * (1.f / NS) - mu * mu;
    float y = (x - mu) * rsqrtf(var + 1e-5f) * lng[i] + lnb[i];
    ob16[t * NS + i] = bf16b(y);
  } else if (bid < PB_W12) {
    // ---- pack_w12: [W1;W2;W0] -> per-kc linear bf16 images ----
    int e = (bid - PB_LN) * 256 + tid;  // < 4*24*320*4 = 122880
    int kg = e & 3;
    int r = e >> 2;
    int nc = r % 320; r /= 320;
    int kc = r % 24;
    int slice = r / 24;
    int oc = origcol(slice, nc);
    int kbase = kc * 32 + kg * 8;
    unsigned short tmp[8];
#pragma unroll
    for (int j = 0; j < 8; ++j) {
      int k = kbase + j;
      float x;
      if (k < 256) x = W1[(size_t)k * NS5 + oc];
      else if (k < 512) x = W2[(size_t)(k - 256) * NS5 + oc];
      else x = W0[(size_t)(k - 512) * NS5 + oc];
      tmp[j] = bf16b(x);
    }
    ushort4 v0 = make_ushort4(tmp[0], tmp[1], tmp[2], tmp[3]);
    ushort4 v1 = make_ushort4(tmp[4], tmp[5], tmp[6], tmp[7]);
    size_t dst = (size_t)(slice * 24 + kc) * 20480 + (size_t)nc * 64 + kg * 16;
    *(ushort4*)((char*)w12p + dst) = v0;
    *(ushort4*)((char*)w12p + dst + 8) = v1;
  } else if (bid < PB_FCW) {
    // ---- pack_fcw: fc_W (512x256 f32) -> bf16 kc-images ----
    int e = (bid - PB_W12) * 256 + tid;  // < 16*256*4 = 16384
    int kg = e & 3;
    int r = e >> 2;
    int nc = r & 255;
    int kc = r >> 8;
    int kbase = kc * 32 + kg * 8;
    unsigned short tmp[8];
#pragma unroll
    for (int j = 0; j < 8; ++j) tmp[j] = bf16b(fcW[(size_t)(kbase + j) * NS + nc]);
    ushort4 v0 = make_ushort4(tmp[0], tmp[1], tmp[2], tmp[3]);
    ushort4 v1 = make_ushort4(tmp[4], tmp[5], tmp[6], tmp[7]);
    size_t dst = (size_t)kc * 16384 + (size_t)nc * 64 + kg * 16;
    *(ushort4*)((char*)fcwp + dst) = v0;
    *(ushort4*)((char*)fcwp + dst + 8) = v1;
  } else {
    // ---- bias: combined z-bias (b1+b2+b0), packed columns ----
    int pc = (bid - PB_FCW) * 256 + tid;
    if (pc < NS5) {
      int slice = pc / 320, nc = pc % 320;
      int oc = origcol(slice, nc);
      bias_zp[pc] = b1[oc] + b2[oc] + b0[oc];
    }
  }
}

// ---------------- Fused tree-level GEMM + LSTM cell ----------------
// Block: 128 rows x 320 packed cols, 4 waves (col-groups); wave tile 128x80.
// acc[8][5] lives in AGPRs (160), so 2 waves/SIMD still fit the unified file.
// A: LDS [2 buf][2 kc][128 rows][64B] = 32KB, XOR-swizzled, 4 DMAs/iter.
// B: registers from L2-resident packed image (R6-proven rotating prefetch).
// Per-iter VMEM order (pinned): [4 A-DMA][5 bnxt][5 bcur]; the compiler's
// bnxt-wait before cluster 2 retires the DMAs; vmcnt(5) is the hard floor.
template <bool FIRST, bool LAST>
__global__ __launch_bounds__(256, 2) void level_kernel(
    const unsigned short* __restrict__ h_in,  // FIRST: ln_b16 table; else (2M,256) bf16
    const unsigned* __restrict__ c_in,        // (M,256) u32 pairs (unused if FIRST)
    const unsigned short* __restrict__ inpx,  // (B*15,256) bf16
    const unsigned short* __restrict__ w12p,  // packed linear weight images
    const float* __restrict__ bias_zp,        // (1280) packed
    unsigned short* __restrict__ h_out,       // (M,256) bf16 (if !LAST)
    unsigned* __restrict__ c_out,             // (M/2,256) u32 pairs (if !LAST)
    unsigned short* __restrict__ state_out,   // (B,256) bf16 (if LAST)
    const int* __restrict__ leaf,             // leaf ids (used if FIRST)
    int log2n, int joff) {
  __shared__ __align__(1024) char ldsA[2 * 16384];
  const int tid = threadIdx.x, lane = tid & 63, wv = tid >> 6;  // wv = col-group
  const int m0 = blockIdx.x * 128;
  const int slice = blockIdx.y;
  const int n = 1 << log2n;

  f32x4 acc[8][5];
#pragma unroll
  for (int a = 0; a < 8; ++a)
#pragma unroll
    for (int t = 0; t < 5; ++t) acc[a][t] = (f32x4){0.f, 0.f, 0.f, 0.f};

  // ---- A staging source bases: this lane stages rows m_lo (j=0) and m_hi (j=1)
  const int rl64 = wv * 16 + (lane >> 2);               // 0..63
  const int ss = (lane & 3) ^ ((rl64 >> 1) & 3);        // pre-swizzled 16B chunk
  const int mlo = m0 + rl64, mhi = mlo + 64;
  const char* h0lo; const char* h1lo; const char* h0hi; const char* h1hi;
  if (FIRST) {
    h0lo = (const char*)h_in + ((size_t)leaf[2 * mlo] * 512 + (size_t)ss * 16);
    h1lo = (const char*)h_in + ((size_t)leaf[2 * mlo + 1] * 512 + (size_t)ss * 16);
    h0hi = (const char*)h_in + ((size_t)leaf[2 * mhi] * 512 + (size_t)ss * 16);
    h1hi = (const char*)h_in + ((size_t)leaf[2 * mhi + 1] * 512 + (size_t)ss * 16);
  } else {
    h0lo = (const char*)h_in + ((size_t)mlo * 1024 + (size_t)ss * 16);
    h1lo = h0lo;
    h0hi = (const char*)h_in + ((size_t)mhi * 1024 + (size_t)ss * 16);
    h1hi = h0hi;
  }
  const char* xlo = (const char*)inpx +
      (((size_t)(mlo >> log2n) * 15 + joff + (mlo & (n - 1))) * 512 + (size_t)ss * 16);
  const char* xhi = (const char*)inpx +
      (((size_t)(mhi >> log2n) * 15 + joff + (mhi & (n - 1))) * 512 + (size_t)ss * 16);
  char* adst = ldsA + wv * 1024;  // wave-uniform; HW appends lane*16

  auto srcA = [&](int kc, int j) -> const char* {
    const char* h0 = j ? h0hi : h0lo;
    const char* h1 = j ? h1hi : h1lo;
    const char* xs = j ? xhi : xlo;
    if (FIRST) {
      return (kc < 8) ? h0 + kc * 64
           : (kc < 16) ? h1 + (kc - 8) * 64
                       : xs + (kc - 16) * 64;
    }
    return (kc < 16) ? h0 + kc * 64 : xs + (kc - 16) * 64;
  };
  auto stageA = [&](int kt, int buf) {  // stages kc = 2kt, 2kt+1 (4 DMAs)
    char* db = adst + buf * 16384;
    g2l16(srcA(2 * kt, 0), db);
    g2l16(srcA(2 * kt, 1), db + 4096);
    g2l16(srcA(2 * kt + 1, 0), db + 8192);
    g2l16(srcA(2 * kt + 1, 1), db + 12288);
  };

  // ---- LDS A-read offset (swizzle invariant under +16 rows => rt*1024 imm) ----
  const int aoff = (lane & 15) * 64 + (((lane >> 4) ^ ((lane >> 1) & 3)) << 4);
  // ---- B global base: 5 coalesced 1KB wave-fragments per kc ----
  const char* gB = (const char*)w12p + (size_t)slice * 24 * 20480 +
                   (size_t)(wv * 80 + (lane & 15)) * 64 + (size_t)(lane >> 4) * 16;

  bf16x8 bcur[5], bnxt[5];
  auto loadB = [&](int kc, bf16x8* dst) {
    const char* gk = gB + (size_t)kc * 20480;
#pragma unroll
    for (int g = 0; g < 5; ++g) dst[g] = *(const bf16x8*)(gk + g * 1024);
  };

#define CLUSTER(pA, bset)                                                           \
  {                                                                                 \
    bf16x8 a0 = *(const bf16x8*)(pA);                                               \
    bf16x8 a1 = *(const bf16x8*)((pA) + 1024);                                      \
    bf16x8 a2 = *(const bf16x8*)((pA) + 2048);                                      \
    bf16x8 a3 = *(const bf16x8*)((pA) + 3072);                                      \
    bf16x8 a4 = *(const bf16x8*)((pA) + 4096);                                      \
    bf16x8 a5 = *(const bf16x8*)((pA) + 5120);                                      \
    bf16x8 a6 = *(const bf16x8*)((pA) + 6144);                                      \
    bf16x8 a7 = *(const bf16x8*)((pA) + 7168);                                      \
    _Pragma("unroll")                                                               \
    for (int g = 0; g < 5; ++g) {                                                   \
      acc[0][g] = __builtin_amdgcn_mfma_f32_16x16x32_bf16(a0, bset[g], acc[0][g], 0, 0, 0); \
      acc[1][g] = __builtin_amdgcn_mfma_f32_16x16x32_bf16(a1, bset[g], acc[1][g], 0, 0, 0); \
      acc[2][g] = __builtin_amdgcn_mfma_f32_16x16x32_bf16(a2, bset[g], acc[2][g], 0, 0, 0); \
      acc[3][g] = __builtin_amdgcn_mfma_f32_16x16x32_bf16(a3, bset[g], acc[3][g], 0, 0, 0); \
      acc[4][g] = __builtin_amdgcn_mfma_f32_16x16x32_bf16(a4, bset[g], acc[4][g], 0, 0, 0); \
      acc[5][g] = __builtin_amdgcn_mfma_f32_16x16x32_bf16(a5, bset[g], acc[5][g], 0, 0, 0); \
      acc[6][g] = __builtin_amdgcn_mfma_f32_16x16x32_bf16(a6, bset[g], acc[6][g], 0, 0, 0); \
      acc[7][g] = __builtin_amdgcn_mfma_f32_16x16x32_bf16(a7, bset[g], acc[7][g], 0, 0, 0); \
    }                                                                               \
  }

  stageA(0, 0);
  loadB(0, bcur);
  asm volatile("s_waitcnt vmcnt(0)" ::: "memory");
  __builtin_amdgcn_s_barrier();

  for (int kt = 0; kt < 12; ++kt) {
    const int buf = kt & 1;
    stageA(kt < 11 ? kt + 1 : 11, buf ^ 1);
    __builtin_amdgcn_sched_barrier(0);
    loadB(2 * kt + 1, bnxt);
    const char* pA = ldsA + buf * 16384 + aoff;
    CLUSTER(pA, bcur);
    loadB(2 * kt + 2 < 24 ? 2 * kt + 2 : 0, bcur);
    CLUSTER(pA + 8192, bnxt);
    __builtin_amdgcn_sched_barrier(0);
    asm volatile("s_waitcnt vmcnt(5)" ::: "memory");
    __builtin_amdgcn_sched_barrier(0);
    __builtin_amdgcn_s_barrier();
  }
#undef CLUSTER

  // ---- Epilogue: lane-local LSTM cell; c via u32 pairs ----
  float bias[5];
#pragma unroll
  for (int g = 0; g < 5; ++g)
    bias[g] = bias_zp[slice * 320 + wv * 80 + g * 16 + (lane & 15)];
  const int u = slice * 64 + wv * 16 + (lane & 15);

#pragma unroll
  for (int rt = 0; rt < 8; ++rt) {
    const int base = m0 + rt * 16 + (lane >> 4) * 4;  // 4 consecutive rows
    float hv[4], cv[4];
#pragma unroll
    for (int r = 0; r < 4; ++r) {
      int row = base + r;
      float za = acc[rt][0][r] + bias[0];
      float zi = acc[rt][1][r] + bias[1];
      float zo = acc[rt][4][r] + bias[4];
      float cnew = tanhfast(za) * sigf(zi);
      if (!FIRST) {
        float zf1 = acc[rt][2][r] + bias[2];
        float zf2 = acc[rt][3][r] + bias[3];
        unsigned pc = c_in[(size_t)row * NS + u];  // (c[2row], c[2row+1])
        float cl = b2f((unsigned short)(pc & 0xffff));
        float cr = b2f((unsigned short)(pc >> 16));
        cnew += sigf(zf1) * cl + sigf(zf2) * cr;
      }
      cv[r] = cnew;
      hv[r] = sigf(zo) * tanhfast(cnew);
    }
    if (LAST) {
#pragma unroll
      for (int r = 0; r < 4; ++r)
        state_out[(size_t)(base + r) * NS + u] = bf16b(hv[r]);
    } else {
#pragma unroll
      for (int r = 0; r < 4; ++r)
        h_out[(size_t)(base + r) * NS + u] = bf16b(hv[r]);
      const size_t pb = (size_t)(base >> 1) * NS + u;
      c_out[pb] = (unsigned)bf16b(cv[0]) | ((unsigned)bf16b(cv[1]) << 16);
      c_out[pb + NS] = (unsigned)bf16b(cv[2]) | ((unsigned)bf16b(cv[3]) << 16);
    }
  }
}

// ---------------- Final head via MFMA ----------------
__global__ __launch_bounds__(256, 2) void fc_mfma(
    const unsigned short* __restrict__ stateb,  // (B,256) bf16
    const unsigned short* __restrict__ ln_b16,  // (T,256) bf16
    const int* __restrict__ action_ids, const unsigned short* __restrict__ fcwp,
    const float* __restrict__ fcb, const float* __restrict__ outW,
    const float* __restrict__ outb, float* __restrict__ out) {
  __shared__ __align__(1024) char ldsA[2 * 8192];
  __shared__ float red[64][4];
  const int tid = threadIdx.x, lane = tid & 63, wv = tid >> 6;
  const int m0 = blockIdx.x * 64;

  f32x4 acc[4][4];
#pragma unroll
  for (int a = 0; a < 4; ++a)
#pragma unroll
    for (int t = 0; t < 4; ++t) acc[a][t] = (f32x4){0.f, 0.f, 0.f, 0.f};

  const int rl = wv * 16 + (lane >> 2);
  const int ss = (lane & 3) ^ ((rl >> 1) & 3);
  const int m = m0 + rl;
  const char* src0 = (const char*)stateb + ((size_t)m * 512 + (size_t)ss * 16);
  const char* src1 =
      (const char*)ln_b16 + ((size_t)action_ids[m] * 512 + (size_t)ss * 16);
  char* adst = ldsA + wv * 1024;

  auto srcA = [&](int kc) -> const char* {
    return (kc < 8) ? src0 + kc * 64 : src1 + (kc - 8) * 64;
  };
  auto stageA = [&](int kt, int buf) {
    g2l16(srcA(2 * kt), adst + buf * 8192);
    g2l16(srcA(2 * kt + 1), adst + buf * 8192 + 4096);
  };

  const int aoff = (lane & 15) * 64 + (((lane >> 4) ^ ((lane >> 1) & 3)) << 4);
  const char* gB = (const char*)fcwp +
                   (size_t)(wv * 64 + (lane & 15)) * 64 + (size_t)(lane >> 4) * 16;

  bf16x8 bcur[4], bnxt[4];
  auto loadB = [&](int kc, bf16x8* dst) {
    const char* gk = gB + (size_t)kc * 16384;
#pragma unroll
    for (int t = 0; t < 4; ++t) dst[t] = *(const bf16x8*)(gk + t * 1024);
  };

  stageA(0, 0);
  loadB(0, bcur);
  asm volatile("s_waitcnt vmcnt(0)" ::: "memory");
  __builtin_amdgcn_s_barrier();

  for (int kt = 0; kt < 8; ++kt) {
    const int buf = kt & 1;
    stageA(kt < 7 ? kt + 1 : 7, buf ^ 1);
    __builtin_amdgcn_sched_barrier(0);
    loadB(2 * kt + 1, bnxt);
    const char* pA = ldsA + buf * 8192 + aoff;
    bf16x8 a0 = *(const bf16x8*)(pA);
    bf16x8 a1 = *(const bf16x8*)(pA + 1024);
    bf16x8 a2 = *(const bf16x8*)(pA + 2048);
    bf16x8 a3 = *(const bf16x8*)(pA + 3072);
#pragma unroll
    for (int t = 0; t < 4; ++t) {
      acc[0][t] = __builtin_amdgcn_mfma_f32_16x16x32_bf16(a0, bcur[t], acc[0][t], 0, 0, 0);
      acc[1][t] = __builtin_amdgcn_mfma_f32_16x16x32_bf16(a1, bcur[t], acc[1][t], 0, 0, 0);
      acc[2][t] = __builtin_amdgcn_mfma_f32_16x16x32_bf16(a2, bcur[t], acc[2][t], 0, 0, 0);
      acc[3][t] = __builtin_amdgcn_mfma_f32_16x16x32_bf16(a3, bcur[t], acc[3][t], 0, 0, 0);
    }
    loadB(2 * kt + 2 < 16 ? 2 * kt + 2 : 0, bcur);
    bf16x8 c0 = *(const bf16x8*)(pA + 4096);
    bf16x8 c1 = *(const bf16x8*)(pA + 5120);
    bf16x8 c2 = *(const bf16x8*)(pA + 6144);
    bf16x8 c3 = *(const bf16x8*)(pA + 7168);
#pragma unroll
    for (int t = 0; t < 4; ++t) {
      acc[0][t] = __builtin_amdgcn_mfma_f32_16x16x32_bf16(c0, bnxt[t], acc[0][t], 0, 0, 0);
      acc[1][t] = __builtin_amdgcn_mfma_f32_16x16x32_bf16(c1, bnxt[t], acc[1][t], 0, 0, 0);
      acc[2][t] = __builtin_amdgcn_mfma_f32_16x16x32_bf16(c2, bnxt[t], acc[2][t], 0, 0, 0);
      acc[3][t] = __builtin_amdgcn_mfma_f32_16x16x32_bf16(c3, bnxt[t], acc[3][t], 0, 0, 0);
    }
    __builtin_amdgcn_sched_barrier(0);
    asm volatile("s_waitcnt vmcnt(4)" ::: "memory");
    __builtin_amdgcn_sched_barrier(0);
    __builtin_amdgcn_s_barrier();
  }

  float fb[4], ow[4];
#pragma unroll
  for (int t = 0; t < 4; ++t) {
    int col = wv * 64 + t * 16 + (lane & 15);
    fb[t] = fcb[col];
    ow[t] = outW[col];
  }
#pragma unroll
  for (int rt = 0; rt < 4; ++rt) {
#pragma unroll
    for (int r = 0; r < 4; ++r) {
      float s = 0.f;
#pragma unroll
      for (int t = 0; t < 4; ++t)
        s += fmaxf(acc[rt][t][r] + fb[t], 0.f) * ow[t];
      s += __shfl_xor(s, 1);
      s += __shfl_xor(s, 2);
      s += __shfl_xor(s, 4);
      s += __shfl_xor(s, 8);
      if ((lane & 15) == 0) red[rt * 16 + (lane >> 4) * 4 + r][wv] = s;
    }
  }
  __syncthreads();
  if (tid < 64)
    out[m0 + tid] = red[tid][0] + red[tid][1] + red[tid][2] + red[tid][3] + outb[0];
}

extern "C" void kernel_launch(void* const* d_in, const int* in_sizes, int n_in,
                              void* d_out, int out_size, void* d_ws, size_t ws_size,
                              hipStream_t stream) {
  const int* leaf_ids = (const int*)d_in[0];
  const int* action_ids = (const int*)d_in[1];
  const float* join_cols = (const float*)d_in[2];
  const float* emb = (const float*)d_in[3];
  const float* ln_g = (const float*)d_in[4];
  const float* ln_b = (const float*)d_in[5];
  const float* jc_W = (const float*)d_in[6];
  const float* jc_b = (const float*)d_in[7];
  const float* W1 = (const float*)d_in[8];
  const float* b1 = (const float*)d_in[9];
  const float* W2 = (const float*)d_in[10];
  const float* b2 = (const float*)d_in[11];
  const float* W0 = (const float*)d_in[12];
  const float* b0 = (const float*)d_in[13];
  const float* fc_W = (const float*)d_in[14];
  const float* fc_b = (const float*)d_in[15];
  const float* out_W = (const float*)d_in[16];
  const float* out_b = (const float*)d_in[17];

  char* ws = (char*)d_ws;
  size_t o = 0;
  auto alloc = [&](size_t bytes) {
    size_t r = o;
    o += (bytes + 255) & ~(size_t)255;
    return r;
  };
  unsigned short* ln_b16 = (unsigned short*)(ws + alloc((size_t)NT * NS * 2));
  unsigned short* w12p = (unsigned short*)(ws + alloc((size_t)4 * 24 * 20480));
  unsigned short* fcwp = (unsigned short*)(ws + alloc((size_t)16 * 16384));
  float* bias_zp = (float*)(ws + alloc((size_t)NS5 * 4));
  unsigned short* inpx = (unsigned short*)(ws + alloc((size_t)NROWS_JC * NS * 2));
  unsigned short* hX = (unsigned short*)(ws + alloc((size_t)NB * 8 * NS * 2));
  unsigned short* hY = (unsigned short*)(ws + alloc((size_t)NB * 4 * NS * 2));
  unsigned* cX = (unsigned*)(ws + alloc((size_t)NB * 8 * NS * 2));
  unsigned* cY = (unsigned*)(ws + alloc((size_t)NB * 4 * NS * 2));
  unsigned short* stateb = (unsigned short*)(ws + alloc((size_t)NB * NS * 2));
  (void)ws_size; (void)in_sizes; (void)n_in; (void)out_size;

  // Fused prologue: inputx + ln + pack_w12 + pack_fcw + bias in one dispatch.
  prologue_kernel<<<PB_TOTAL, 256, 0, stream>>>(
      join_cols, jc_W, jc_b, inpx, emb, ln_g, ln_b, ln_b16, W1, W2, W0, w12p,
      fc_W, fcwp, b1, b2, b0, bias_zp);

  // Level 0: n=8, off=0, M=65536
  level_kernel<true, false><<<dim3(512, 4), 256, 0, stream>>>(
      ln_b16, nullptr, inpx, w12p, bias_zp, hX, cX, nullptr, leaf_ids, 3, 0);
  // Level 1: n=4, off=8, M=32768
  level_kernel<false, false><<<dim3(256, 4), 256, 0, stream>>>(
      hX, cX, inpx, w12p, bias_zp, hY, cY, nullptr, leaf_ids, 2, 8);
  // Level 2: n=2, off=12, M=16384
  level_kernel<false, false><<<dim3(128, 4), 256, 0, stream>>>(
      hY, cY, inpx, w12p, bias_zp, hX, cX, nullptr, leaf_ids, 1, 12);
  // Level 3: n=1, off=14, M=8192 -> state bf16
  level_kernel<false, true><<<dim3(64, 4), 256, 0, stream>>>(
      hX, cX, inpx, w12p, bias_zp, nullptr, nullptr, stateb, leaf_ids, 0, 14);

  fc_mfma<<<NB / 64, 256, 0, stream>>>(stateb, ln_b16, action_ids, fcwp, fc_b,
                                       out_W, out_b, (float*)d_out);
}